// Round 2
// 11567.494 us; speedup vs baseline: 1.5707x; 1.5707x over previous
//
#include <hip/hip_runtime.h>
#include <cstdint>

#define SSP   13294      // total spatial tokens (100^2+50^2+25^2+13^2)
#define NROW  2400       // B*NQ
#define NROWP 2432

typedef double v4d __attribute__((ext_vector_type(4)));

__device__ __forceinline__ double sigd(double x) { return 1.0 / (1.0 + exp(-x)); }
__device__ __forceinline__ double invsigd(double x) {
    x = fmin(fmax(x, 0.0), 1.0);
    return log(fmax(x, 1e-5) / fmax(1.0 - x, 1e-5));
}
__device__ __forceinline__ double rdA(const float* a, size_t k) { return (double)a[k]; }
__device__ __forceinline__ double rdA(const double* a, size_t k) { return a[k]; }

// Self-calibrating probe for the f64 MFMA C/D row mapping.
// Feed A[i][k] = i (a = lane&15 works because A lane = i + 16k),
// B[k][j] = 0.25 (uniform -> B layout irrelevant). Then D[i][j] = i exactly,
// so the observed d[r] is THE true output row for register r of this lane.
__device__ __forceinline__ void mfma_rowmap(int lane, int* rm) {
    v4d c = {0., 0., 0., 0.};
    double a = (double)(lane & 15);
    c = __builtin_amdgcn_mfma_f64_16x16x4f64(a, 0.25, c, 0, 0, 0);
#pragma unroll
    for (int r = 0; r < 4; r++) rm[r] = (int)(c[r] + 0.5);
}

// ---- fp64 MFMA GEMM: C (+)= relu?(A(MxK) @ W(NxK)^T + bias) -----------------
// 64x64 block tile, 4 waves, each wave one 32x32 quadrant = 2x2 mfma_f64_16x16x4
// LDS K-transposed [16][66]
template<typename TA, bool RELU, bool ACC>
__global__ __launch_bounds__(256)
void mgemm(const TA* __restrict__ A, int lda,
           const float* __restrict__ W, int ldb,
           const float* __restrict__ bias,
           float* __restrict__ C, int ldc,
           int M, int N, int K)
{
    __shared__ double As[16][66];
    __shared__ double Bs[16][66];
    int bm = blockIdx.x * 64, bn = blockIdx.y * 64;
    int tid = threadIdx.x;
    int lane = tid & 63, wave = tid >> 6;
    int wm = (wave >> 1) * 32, wn = (wave & 1) * 32;
    int j = lane & 15, q = lane >> 4;       // A row / B col = j, k-quarter = q
    int kk = tid & 15, r0 = tid >> 4;       // staging: k = kk (coalesced), row = r0+16rr
    int rowmap[4];
    mfma_rowmap(lane, rowmap);
    v4d acc[2][2];
#pragma unroll
    for (int fm = 0; fm < 2; fm++)
#pragma unroll
        for (int fn = 0; fn < 2; fn++)
#pragma unroll
            for (int i = 0; i < 4; i++) acc[fm][fn][i] = 0.0;

    for (int k0 = 0; k0 < K; k0 += 16) {
#pragma unroll
        for (int rr = 0; rr < 4; rr++) {
            int r = r0 + rr * 16;
            int am = bm + r; if (am > M - 1) am = M - 1;
            As[kk][r] = rdA(A, (size_t)am * lda + k0 + kk);
            int wn_ = bn + r; if (wn_ > N - 1) wn_ = N - 1;
            Bs[kk][r] = (double)W[(size_t)wn_ * ldb + k0 + kk];
        }
        __syncthreads();
#pragma unroll
        for (int kst = 0; kst < 4; kst++) {
            int krow = kst * 4 + q;
            double a0 = As[krow][wm + j];
            double a1 = As[krow][wm + 16 + j];
            double b0 = Bs[krow][wn + j];
            double b1 = Bs[krow][wn + 16 + j];
            acc[0][0] = __builtin_amdgcn_mfma_f64_16x16x4f64(a0, b0, acc[0][0], 0, 0, 0);
            acc[0][1] = __builtin_amdgcn_mfma_f64_16x16x4f64(a0, b1, acc[0][1], 0, 0, 0);
            acc[1][0] = __builtin_amdgcn_mfma_f64_16x16x4f64(a1, b0, acc[1][0], 0, 0, 0);
            acc[1][1] = __builtin_amdgcn_mfma_f64_16x16x4f64(a1, b1, acc[1][1], 0, 0, 0);
        }
        __syncthreads();
    }
    // D layout: col = lane&15, row = rowmap[reg]  (probed at runtime)
#pragma unroll
    for (int fm = 0; fm < 2; fm++)
#pragma unroll
        for (int fn = 0; fn < 2; fn++)
#pragma unroll
            for (int i = 0; i < 4; i++) {
                int gm = bm + wm + fm * 16 + rowmap[i];
                int gn = bn + wn + fn * 16 + j;
                if (gm < M && gn < N) {
                    double v = acc[fm][fn][i] + (bias ? (double)bias[gn] : 0.0);
                    if (ACC) v += (double)C[(size_t)gm * ldc + gn];
                    if (RELU) v = fmax(v, 0.0);
                    C[(size_t)gm * ldc + gn] = (float)v;
                }
            }
}

template<typename TA, bool RELU, bool ACC>
static void launch_m(hipStream_t st, const TA* A, int lda, const float* W, int ldb,
                     const float* bias, float* C, int ldc, int M, int N, int K)
{
    dim3 grid((M + 63) / 64, (N + 63) / 64, 1);
    mgemm<TA, RELU, ACC><<<grid, 256, 0, st>>>(A, lda, W, ldb, bias, C, ldc, M, N, K);
}

// -- value GEMM (MFMA), fused NCHW->token gather; batch b, channels [c0,c0+64) -
__global__ __launch_bounds__(256)
void value_mgemm(const float* __restrict__ s0, const float* __restrict__ s1,
                 const float* __restrict__ s2, const float* __restrict__ s3,
                 int b, const float* __restrict__ W, const float* __restrict__ bias,
                 float* __restrict__ outv, int c0)
{
    __shared__ double As[16][66];
    __shared__ double Bs[16][66];
    int bm = blockIdx.x * 64;
    int tid = threadIdx.x;
    int lane = tid & 63, wave = tid >> 6;
    int wm = (wave >> 1) * 32, wn = (wave & 1) * 32;
    int j = lane & 15, q = lane >> 4;
    // A: source is channel-plane (NCHW) -> stage token-contiguous for coalescing
    int ka = tid >> 4, ra0 = tid & 15;
    // B: weights are [N][K] row-major -> stage k-contiguous
    int kb = tid & 15, rb0 = tid >> 4;
    int rowmap[4];
    mfma_rowmap(lane, rowmap);
    v4d acc[2][2];
#pragma unroll
    for (int fm = 0; fm < 2; fm++)
#pragma unroll
        for (int fn = 0; fn < 2; fn++)
#pragma unroll
            for (int i = 0; i < 4; i++) acc[fm][fn][i] = 0.0;

    for (int k0 = 0; k0 < 256; k0 += 16) {
#pragma unroll
        for (int rr = 0; rr < 4; rr++) {
            int ra = ra0 + rr * 16;
            int t = bm + ra; if (t > SSP - 1) t = SSP - 1;
            const float* sb; int hw, s;
            if (t < 10000)      { sb = s0; hw = 10000; s = t; }
            else if (t < 12500) { sb = s1; hw = 2500;  s = t - 10000; }
            else if (t < 13125) { sb = s2; hw = 625;   s = t - 12500; }
            else                { sb = s3; hw = 169;   s = t - 13125; }
            As[ka][ra] = (double)sb[(size_t)(b * 256 + k0 + ka) * hw + s];
            int rb = rb0 + rr * 16;
            Bs[kb][rb] = (double)W[(size_t)(c0 + rb) * 256 + k0 + kb];
        }
        __syncthreads();
#pragma unroll
        for (int kst = 0; kst < 4; kst++) {
            int krow = kst * 4 + q;
            double a0 = As[krow][wm + j];
            double a1 = As[krow][wm + 16 + j];
            double b0 = Bs[krow][wn + j];
            double b1 = Bs[krow][wn + 16 + j];
            acc[0][0] = __builtin_amdgcn_mfma_f64_16x16x4f64(a0, b0, acc[0][0], 0, 0, 0);
            acc[0][1] = __builtin_amdgcn_mfma_f64_16x16x4f64(a0, b1, acc[0][1], 0, 0, 0);
            acc[1][0] = __builtin_amdgcn_mfma_f64_16x16x4f64(a1, b0, acc[1][0], 0, 0, 0);
            acc[1][1] = __builtin_amdgcn_mfma_f64_16x16x4f64(a1, b1, acc[1][1], 0, 0, 0);
        }
        __syncthreads();
    }
#pragma unroll
    for (int fm = 0; fm < 2; fm++)
#pragma unroll
        for (int fn = 0; fn < 2; fn++)
#pragma unroll
            for (int i = 0; i < 4; i++) {
                int gm = bm + wm + fm * 16 + rowmap[i];
                int gn = wn + fn * 16 + j;
                if (gm < SSP)
                    outv[(size_t)gm * 64 + gn] = (float)(acc[fm][fn][i] + (double)bias[c0 + gn]);
            }
}

// ---------------- MHA, fp64 math, wave-parallel softmax -----------------------
__global__ __launch_bounds__(320)
void naive_mha(const float* __restrict__ qk, const float* __restrict__ vbuf,
               float* __restrict__ mha)
{
    int row = blockIdx.x;
    int b = row / 300;
    int h = blockIdx.y;
    const double scale = 0.17677669529663687;
    __shared__ double sc[304];
    __shared__ double red[8];
    __shared__ double ob[10][33];
    int j = threadIdx.x;
    double s = -1e300;
    if (j < 300) {
        const float* qp = qk + (size_t)row * 512 + h * 32;
        const float* kp = qk + (size_t)(b * 300 + j) * 512 + 256 + h * 32;
        double t = 0.;
#pragma unroll
        for (int d = 0; d < 32; d++) t += (double)qp[d] * (double)kp[d];
        sc[j] = t; s = t;
    }
#pragma unroll
    for (int o = 32; o > 0; o >>= 1) s = fmax(s, __shfl_xor(s, o));
    int wv = j >> 6;
    if ((j & 63) == 0) red[wv] = s;
    __syncthreads();
    double mx = fmax(fmax(fmax(red[0], red[1]), fmax(red[2], red[3])), red[4]);
    double e = 0.;
    if (j < 300) { e = exp((sc[j] - mx) * scale); sc[j] = e; }
    double se = e;
#pragma unroll
    for (int o = 32; o > 0; o >>= 1) se += __shfl_xor(se, o);
    __syncthreads();                      // everyone done reading red (mx)
    if ((j & 63) == 0) red[wv] = se;
    __syncthreads();
    double inv = 1.0 / (red[0] + red[1] + red[2] + red[3] + red[4]);
    // PV: 10 stripes x 32 channels over all 320 threads
    int d = j & 31, g = j >> 5;
    double o = 0.;
    const float* vp = vbuf + (size_t)(b * 300) * 256 + h * 32 + d;
    for (int t = g; t < 300; t += 10) o += sc[t] * (double)vp[(size_t)t * 256];
    ob[g][d] = o;
    __syncthreads();
    if (j < 32) {
        double acc2 = 0.;
#pragma unroll
        for (int g2 = 0; g2 < 10; g2++) acc2 += ob[g2][j];
        mha[(size_t)row * 256 + h * 32 + j] = (float)(acc2 * inv);
    }
}

// ---------------- small-N GEMMs, fp64 math ------------------------------------
__global__ __launch_bounds__(256)
void gemm_small_qe(const float* __restrict__ qe, const float* __restrict__ W,
                   const float* __restrict__ bias, float* __restrict__ out, int N, int M)
{
    int t = blockIdx.x * 256 + threadIdx.x;
    if (t >= M * N) return;
    int row = t / N, n = t % N;
    const float* a = qe + (size_t)(row % 300) * 512;   // qpos = query_embed[:, :256]
    const float* w = W + (size_t)n * 256;
    double s = 0.0;
    for (int k = 0; k < 256; k++) s += (double)a[k] * (double)w[k];
    out[t] = (float)(s + (double)bias[n]);
}
__global__ __launch_bounds__(256)
void gemm_smallN(const float* __restrict__ A, int lda, const float* __restrict__ W,
                 const float* __restrict__ bias, float* __restrict__ out, int N, int M)
{
    int t = blockIdx.x * 256 + threadIdx.x;
    if (t >= M * N) return;
    int row = t / N, n = t % N;
    const float* a = A + (size_t)row * lda;
    const float* w = W + (size_t)n * 256;
    double s = 0.0;
    for (int k = 0; k < 256; k++) s += (double)a[k] * (double)w[k];
    out[t] = (float)(s + (double)bias[n]);
}

// ---------------- tgt init (fp64 residual stream) -----------------------------
__global__ __launch_bounds__(256)
void init_tgt(const float* __restrict__ qe, double* __restrict__ tgt)
{
    int row = blockIdx.x, c = threadIdx.x;
    size_t i = (size_t)row * 256 + c;
    tgt[i] = (row < NROW) ? (double)qe[(size_t)(row % 300) * 512 + 256 + c] : 0.0;
}

// qin = tgt + qpos (qpos read straight from query_embed)
__global__ void add_q(const double* __restrict__ tgt, const float* __restrict__ qe,
                      float* __restrict__ qin)
{
    int row = blockIdx.x, c = threadIdx.x;
    size_t i = (size_t)row * 256 + c;
    qin[i] = (float)(tgt[i] + (double)qe[(size_t)(row % 300) * 512 + c]);
}

// ---------------- fused residual-add + LayerNorm, fp64 math -------------------
__global__ __launch_bounds__(256)
void add_ln(double* __restrict__ tgt, const float* __restrict__ br,
            const float* __restrict__ w, const float* __restrict__ b,
            float* __restrict__ hs_out)
{
    int row = blockIdx.x, c = threadIdx.x;
    size_t idx = (size_t)row * 256 + c;
    double v = tgt[idx] + (double)br[idx];
    double s = v, s2 = v * v;
#pragma unroll
    for (int o = 32; o > 0; o >>= 1) { s += __shfl_xor(s, o); s2 += __shfl_xor(s2, o); }
    __shared__ double rs[4], rs2[4];
    int wv = c >> 6;
    if ((c & 63) == 0) { rs[wv] = s; rs2[wv] = s2; }
    __syncthreads();
    double S = rs[0] + rs[1] + rs[2] + rs[3];
    double S2 = rs2[0] + rs2[1] + rs2[2] + rs2[3];
    double mean = S * (1.0 / 256.0);
    double var = S2 * (1.0 / 256.0) - mean * mean;
    double o = (v - mean) / sqrt(var + 1e-5) * (double)w[c] + (double)b[c];
    tgt[idx] = o;
    if (hs_out) hs_out[idx] = (float)o;
}

// ---------------- attention-weight softmax over 16 per (row,h), fp64 ----------
__global__ __launch_bounds__(256)
void aw_softmax(float* __restrict__ buf)
{
    int t = blockIdx.x * 256 + threadIdx.x;
    if (t >= NROW * 8) return;
    int row = t >> 3, h = t & 7;
    float* p = buf + (size_t)row * 128 + h * 16;
    double mx = -1e300, e[16];
#pragma unroll
    for (int j = 0; j < 16; j++) mx = fmax(mx, (double)p[j]);
    double s = 0.;
#pragma unroll
    for (int j = 0; j < 16; j++) { e[j] = exp((double)p[j] - mx); s += e[j]; }
    double inv = 1.0 / s;
#pragma unroll
    for (int j = 0; j < 16; j++) p[j] = (float)(e[j] * inv);
}

// ------ deformable bilinear sampler, fp64 math, value slice 64 ch (2 heads) ----
__global__ __launch_bounds__(64)
void deform_sample(const float* __restrict__ value, int h0,
                   const float* __restrict__ offb, const float* __restrict__ awsm,
                   const double* __restrict__ ref, float* __restrict__ out, int row0)
{
    int row = row0 + blockIdx.x;
    int hl = threadIdx.x >> 5, d = threadIdx.x & 31;
    int h = h0 + hl;
    double rx = ref[row * 4 + 0], ry = ref[row * 4 + 1];
    double rw = ref[row * 4 + 2], rh = ref[row * 4 + 3];
    const float* offr = offb + (size_t)row * 256;
    const float* awr = awsm + (size_t)row * 128 + h * 16;
    size_t vbase = hl * 32 + d;
    const int LH[4] = {100, 50, 25, 13};
    const int LW[4] = {100, 50, 25, 13};
    const int LS[4] = {0, 10000, 12500, 13125};
    double acc = 0.;
#pragma unroll
    for (int l = 0; l < 4; l++) {
        int Hh = LH[l], Ww = LW[l], st = LS[l];
#pragma unroll
        for (int p = 0; p < 4; p++) {
            double ox = (double)offr[(h * 32) + l * 8 + p * 2 + 0];
            double oy = (double)offr[(h * 32) + l * 8 + p * 2 + 1];
            double aw = (double)awr[l * 4 + p];
            double x = (rx + ox * 0.125 * rw) * Ww - 0.5;
            double y = (ry + oy * 0.125 * rh) * Hh - 0.5;
            double xf = floor(x), yf = floor(y);
            double dx = x - xf, dy = y - yf;
            int x0 = (int)xf, y0 = (int)yf;
            double w00 = (1 - dx) * (1 - dy), w10 = dx * (1 - dy);
            double w01 = (1 - dx) * dy, w11 = dx * dy;
#define CORN(X, Y, W)                                                              \
            if ((unsigned)(X) < (unsigned)Ww && (unsigned)(Y) < (unsigned)Hh)      \
                acc += (W) * aw * (double)value[vbase + (size_t)(st + (Y) * Ww + (X)) * 64];
            CORN(x0, y0, w00) CORN(x0 + 1, y0, w10) CORN(x0, y0 + 1, w01) CORN(x0 + 1, y0 + 1, w11)
#undef CORN
        }
    }
    out[(size_t)row * 256 + h * 32 + d] = (float)acc;
}

// ---------------- ref init / update (fp64 state, fp32 refs out) ---------------
__global__ void ref_init(const float* __restrict__ lin2, const float* __restrict__ bb,
                         double* __restrict__ ref)
{
    int t = blockIdx.x * 256 + threadIdx.x;
    if (t >= NROW) return;
#pragma unroll
    for (int j = 0; j < 2; j++) {
        double r2 = sigd((double)lin2[t * 2 + j]);
        ref[t * 4 + j] = sigd((double)bb[t * 4 + j] + invsigd(r2));
    }
    ref[t * 4 + 2] = sigd((double)bb[t * 4 + 2]);
    ref[t * 4 + 3] = sigd((double)bb[t * 4 + 3]);
}
__global__ void ref_update(const float* __restrict__ bb, double* __restrict__ ref,
                           float* __restrict__ refs_out)
{
    int t = blockIdx.x * 256 + threadIdx.x;
    if (t >= NROW * 4) return;
    double nv = sigd((double)bb[t] + invsigd(ref[t]));
    ref[t] = nv;
    refs_out[t] = (float)nv;
}

// =============================== launcher =====================================
extern "C" void kernel_launch(void* const* d_in, const int* in_sizes, int n_in,
                              void* d_out, int out_size, void* d_ws, size_t ws_size,
                              hipStream_t stream)
{
    const float* src0 = (const float*)d_in[0];
    const float* src1 = (const float*)d_in[2];
    const float* src2 = (const float*)d_in[4];
    const float* src3 = (const float*)d_in[6];
    const float* qe = (const float*)d_in[8];
    const float* ref_w = (const float*)d_in[9];
    const float* ref_b = (const float*)d_in[10];
    const float* sa_in_w = (const float*)d_in[11];
    const float* sa_in_b = (const float*)d_in[12];
    const float* sa_out_w = (const float*)d_in[13];
    const float* sa_out_b = (const float*)d_in[14];
    const float* off_w = (const float*)d_in[15];
    const float* off_b = (const float*)d_in[16];
    const float* aw_w = (const float*)d_in[17];
    const float* aw_b = (const float*)d_in[18];
    const float* val_w = (const float*)d_in[19];
    const float* val_b = (const float*)d_in[20];
    const float* cao_w = (const float*)d_in[21];
    const float* cao_b = (const float*)d_in[22];
    const float* ln1_w = (const float*)d_in[23];
    const float* ln1_b = (const float*)d_in[24];
    const float* ln2_w = (const float*)d_in[25];
    const float* ln2_b = (const float*)d_in[26];
    const float* ln3_w = (const float*)d_in[27];
    const float* ln3_b = (const float*)d_in[28];
    const float* ff1_w = (const float*)d_in[29];
    const float* ff1_b = (const float*)d_in[30];
    const float* ff2_w = (const float*)d_in[31];
    const float* ff2_b = (const float*)d_in[32];
    const float* bb_w1 = (const float*)d_in[33];
    const float* bb_b1 = (const float*)d_in[34];
    const float* bb_w2 = (const float*)d_in[35];
    const float* bb_b2 = (const float*)d_in[36];
    const float* bb_w3 = (const float*)d_in[37];
    const float* bb_b3 = (const float*)d_in[38];
    const float* cls_w = (const float*)d_in[39];
    const float* cls_b = (const float*)d_in[40];

    char* wsp = (char*)d_ws;
    size_t off_ws = 0;
    auto alloc = [&](size_t bytes) -> char* {
        char* p = wsp + off_ws;
        off_ws += (bytes + 255) & ~(size_t)255;
        return p;
    };
    // lean layout, ~21.0 MB total (ws >= 23 MB proven by round-7 probe)
    float* value = (float*)alloc((size_t)SSP * 64 * 4);      // 3.40 MB (batch, 64-ch slice)
    double* tgt  = (double*)alloc((size_t)NROWP * 256 * 8);  // 4.98 MB fp64 residual stream
    float* proj = (float*)alloc((size_t)NROWP * 256 * 4);    // 2.49
    char* bigA = alloc((size_t)NROWP * 512 * 4);             // 4.98 union
    float* qk   = (float*)bigA;                              //  qk 512 (self-attn)
    float* ffnh = (float*)bigA;                              //  ffnh 512-split (FFN)
    float* offb = (float*)bigA;                              //  offb 256 (deform)
    float* awb  = (float*)(bigA + (size_t)NROWP * 256 * 4);  //  awb 128 (deform)
    char* bufB = alloc((size_t)NROWP * 256 * 4);             // 2.49 union
    float* vbuf = (float*)bufB;
    float* samp = (float*)bufB;
    float* bh1  = (float*)bufB;
    char* bufC = alloc((size_t)NROWP * 256 * 4);             // 2.49 union
    float* qin = (float*)bufC;
    float* mha = (float*)bufC;
    float* bh2 = (float*)bufC;
    float* bb4   = (float*)alloc((size_t)NROWP * 4 * 4);
    double* refb = (double*)alloc((size_t)NROWP * 4 * 8);
    float* rlin2 = (float*)alloc((size_t)NROWP * 2 * 4);

    float* out_f = (float*)d_out;                            // fp32 outputs
    float* hs_out = out_f;                                   // 6 * 614400
    float* refs_out = out_f + (size_t)6 * 614400;            // 6 * 9600
    float* log_out = refs_out + (size_t)6 * 9600;            // 6 * 194400

    // ---- setup ----
    init_tgt<<<NROWP, 256, 0, stream>>>(qe, tgt);
    gemm_small_qe<<<(NROW * 2 + 255) / 256, 256, 0, stream>>>(qe, ref_w, ref_b, rlin2, 2, NROW);
    launch_m<double, true, false>(stream, tgt, 256, bb_w1, 256, bb_b1, bh1, 256, NROW, 256, 256);
    launch_m<float, true, false>(stream, bh1, 256, bb_w2, 256, bb_b2, proj, 256, NROW, 256, 256);
    gemm_smallN<<<(NROW * 4 + 255) / 256, 256, 0, stream>>>(proj, 256, bb_w3, bb_b3, bb4, 4, NROW);
    ref_init<<<(NROW + 255) / 256, 256, 0, stream>>>(rlin2, bb4, refb);

    for (int i = 0; i < 6; i++) {
        // ---- self attention: qin(bufC) -> qk(bigA); vbuf(bufB); mha(bufC over qin) ----
        add_q<<<NROW, 256, 0, stream>>>(tgt, qe, qin);
        launch_m<float, false, false>(stream, qin, 256, sa_in_w + (size_t)i * 196608, 256,
                                      sa_in_b + i * 768, qk, 512, NROW, 512, 256);
        launch_m<double, false, false>(stream, tgt, 256, sa_in_w + (size_t)i * 196608 + 131072, 256,
                                       sa_in_b + i * 768 + 512, vbuf, 256, NROW, 256, 256);
        naive_mha<<<dim3(NROW, 8), 320, 0, stream>>>(qk, vbuf, mha);
        launch_m<float, false, false>(stream, mha, 256, sa_out_w + (size_t)i * 65536, 256,
                                      sa_out_b + i * 256, proj, 256, NROW, 256, 256);
        add_ln<<<NROW, 256, 0, stream>>>(tgt, proj, ln2_w + i * 256, ln2_b + i * 256, nullptr);

        // ---- deformable cross attention: qin(bufC), offb/awb(bigA), samp(bufB) ----
        add_q<<<NROW, 256, 0, stream>>>(tgt, qe, qin);
        launch_m<float, false, false>(stream, qin, 256, off_w + (size_t)i * 65536, 256,
                                      off_b + i * 256, offb, 256, NROW, 256, 256);
        launch_m<float, false, false>(stream, qin, 256, aw_w + (size_t)i * 32768, 256,
                                      aw_b + i * 128, awb, 128, NROW, 128, 256);
        aw_softmax<<<(NROW * 8 + 255) / 256, 256, 0, stream>>>(awb);
        for (int b = 0; b < 8; b++) {
            for (int s = 0; s < 4; s++) {
                value_mgemm<<<dim3((SSP + 63) / 64, 1), 256, 0, stream>>>(
                    src0, src1, src2, src3, b, val_w + (size_t)i * 65536, val_b + i * 256,
                    value, s * 64);
                deform_sample<<<300, 64, 0, stream>>>(value, s * 2, offb, awb, refb,
                                                      samp, b * 300);
            }
        }
        launch_m<float, false, false>(stream, samp, 256, cao_w + (size_t)i * 65536, 256,
                                      cao_b + i * 256, proj, 256, NROW, 256, 256);
        add_ln<<<NROW, 256, 0, stream>>>(tgt, proj, ln1_w + i * 256, ln1_b + i * 256, nullptr);

        // ---- FFN, hidden split 2x512 into ffnh(bigA) ----
        launch_m<double, true, false>(stream, tgt, 256, ff1_w + (size_t)i * 262144, 256,
                                      ff1_b + i * 1024, ffnh, 512, NROW, 512, 256);
        launch_m<float, false, false>(stream, ffnh, 512, ff2_w + (size_t)i * 262144, 1024,
                                      ff2_b + i * 256, proj, 256, NROW, 256, 512);
        launch_m<double, true, false>(stream, tgt, 256, ff1_w + (size_t)i * 262144 + 512 * 256, 256,
                                      ff1_b + i * 1024 + 512, ffnh, 512, NROW, 512, 256);
        launch_m<float, false, true>(stream, ffnh, 512, ff2_w + (size_t)i * 262144 + 512, 1024,
                                     nullptr, proj, 256, NROW, 256, 512);
        add_ln<<<NROW, 256, 0, stream>>>(tgt, proj, ln3_w + i * 256, ln3_b + i * 256,
                                         hs_out + (size_t)i * 614400);

        // ---- bbox refinement: bh1(bufB), bh2(bufC) ----
        launch_m<double, true, false>(stream, tgt, 256, bb_w1 + (size_t)(i + 1) * 65536, 256,
                                      bb_b1 + (i + 1) * 256, bh1, 256, NROW, 256, 256);
        launch_m<float, true, false>(stream, bh1, 256, bb_w2 + (size_t)(i + 1) * 65536, 256,
                                     bb_b2 + (i + 1) * 256, bh2, 256, NROW, 256, 256);
        gemm_smallN<<<(NROW * 4 + 255) / 256, 256, 0, stream>>>(
            bh2, 256, bb_w3 + (size_t)(i + 1) * 1024, bb_b3 + (i + 1) * 4, bb4, 4, NROW);
        ref_update<<<(NROW * 4 + 255) / 256, 256, 0, stream>>>(bb4, refb, refs_out + (size_t)i * 9600);

        // ---- logits ----
        launch_m<double, false, false>(stream, tgt, 256, cls_w + (size_t)(i + 1) * 20736, 256,
                                       cls_b + (i + 1) * 81, log_out + (size_t)i * 194400,
                                       81, NROW, 81, 256);
    }
}

// Round 3
// 8147.624 us; speedup vs baseline: 2.2300x; 1.4197x over previous
//
#include <hip/hip_runtime.h>
#include <cstdint>

#define SSP   13294      // total spatial tokens (100^2+50^2+25^2+13^2)
#define NROW  2400       // B*NQ
#define NROWP 2432

typedef double v4d __attribute__((ext_vector_type(4)));

__device__ __forceinline__ double sigd(double x) { return 1.0 / (1.0 + exp(-x)); }
__device__ __forceinline__ double invsigd(double x) {
    x = fmin(fmax(x, 0.0), 1.0);
    return log(fmax(x, 1e-5) / fmax(1.0 - x, 1e-5));
}
__device__ __forceinline__ double rdA(const float* a, size_t k) { return (double)a[k]; }
__device__ __forceinline__ double rdA(const double* a, size_t k) { return a[k]; }

// Self-calibrating probe for the f64 MFMA C/D row mapping (verified working r2).
__device__ __forceinline__ void mfma_rowmap(int lane, int* rm) {
    v4d c = {0., 0., 0., 0.};
    double a = (double)(lane & 15);
    c = __builtin_amdgcn_mfma_f64_16x16x4f64(a, 0.25, c, 0, 0, 0);
#pragma unroll
    for (int r = 0; r < 4; r++) rm[r] = (int)(c[r] + 0.5);
}

// ---- fp64 MFMA GEMM: C (+)= relu?(A(MxK) @ W(NxK)^T + bias) -----------------
template<typename TA, bool RELU, bool ACC>
__global__ __launch_bounds__(256)
void mgemm(const TA* __restrict__ A, int lda,
           const float* __restrict__ W, int ldb,
           const float* __restrict__ bias,
           float* __restrict__ C, int ldc,
           int M, int N, int K)
{
    __shared__ double As[16][66];
    __shared__ double Bs[16][66];
    int bm = blockIdx.x * 64, bn = blockIdx.y * 64;
    int tid = threadIdx.x;
    int lane = tid & 63, wave = tid >> 6;
    int wm = (wave >> 1) * 32, wn = (wave & 1) * 32;
    int j = lane & 15, q = lane >> 4;
    int kk = tid & 15, r0 = tid >> 4;
    int rowmap[4];
    mfma_rowmap(lane, rowmap);
    v4d acc[2][2];
#pragma unroll
    for (int fm = 0; fm < 2; fm++)
#pragma unroll
        for (int fn = 0; fn < 2; fn++)
#pragma unroll
            for (int i = 0; i < 4; i++) acc[fm][fn][i] = 0.0;

    for (int k0 = 0; k0 < K; k0 += 16) {
#pragma unroll
        for (int rr = 0; rr < 4; rr++) {
            int r = r0 + rr * 16;
            int am = bm + r; if (am > M - 1) am = M - 1;
            As[kk][r] = rdA(A, (size_t)am * lda + k0 + kk);
            int wn_ = bn + r; if (wn_ > N - 1) wn_ = N - 1;
            Bs[kk][r] = (double)W[(size_t)wn_ * ldb + k0 + kk];
        }
        __syncthreads();
#pragma unroll
        for (int kst = 0; kst < 4; kst++) {
            int krow = kst * 4 + q;
            double a0 = As[krow][wm + j];
            double a1 = As[krow][wm + 16 + j];
            double b0 = Bs[krow][wn + j];
            double b1 = Bs[krow][wn + 16 + j];
            acc[0][0] = __builtin_amdgcn_mfma_f64_16x16x4f64(a0, b0, acc[0][0], 0, 0, 0);
            acc[0][1] = __builtin_amdgcn_mfma_f64_16x16x4f64(a0, b1, acc[0][1], 0, 0, 0);
            acc[1][0] = __builtin_amdgcn_mfma_f64_16x16x4f64(a1, b0, acc[1][0], 0, 0, 0);
            acc[1][1] = __builtin_amdgcn_mfma_f64_16x16x4f64(a1, b1, acc[1][1], 0, 0, 0);
        }
        __syncthreads();
    }
#pragma unroll
    for (int fm = 0; fm < 2; fm++)
#pragma unroll
        for (int fn = 0; fn < 2; fn++)
#pragma unroll
            for (int i = 0; i < 4; i++) {
                int gm = bm + wm + fm * 16 + rowmap[i];
                int gn = bn + wn + fn * 16 + j;
                if (gm < M && gn < N) {
                    double v = acc[fm][fn][i] + (bias ? (double)bias[gn] : 0.0);
                    if (ACC) v += (double)C[(size_t)gm * ldc + gn];
                    if (RELU) v = fmax(v, 0.0);
                    C[(size_t)gm * ldc + gn] = (float)v;
                }
            }
}

template<typename TA, bool RELU, bool ACC>
static void launch_m(hipStream_t st, const TA* A, int lda, const float* W, int ldb,
                     const float* bias, float* C, int ldc, int M, int N, int K)
{
    dim3 grid((M + 63) / 64, (N + 63) / 64, 1);
    mgemm<TA, RELU, ACC><<<grid, 256, 0, st>>>(A, lda, W, ldb, bias, C, ldc, M, N, K);
}

// -- value GEMM (MFMA), fused NCHW->token gather; batches [b0,b0+2), ch [c0,c0+64)
__global__ __launch_bounds__(256)
void value_mgemm(const float* __restrict__ s0, const float* __restrict__ s1,
                 const float* __restrict__ s2, const float* __restrict__ s3,
                 int b0, const float* __restrict__ W, const float* __restrict__ bias,
                 float* __restrict__ outv, int c0)
{
    __shared__ double As[16][66];
    __shared__ double Bs[16][66];
    int bm = blockIdx.x * 64;
    int b = b0 + blockIdx.y;
    size_t obase = (size_t)blockIdx.y * SSP * 64;
    int tid = threadIdx.x;
    int lane = tid & 63, wave = tid >> 6;
    int wm = (wave >> 1) * 32, wn = (wave & 1) * 32;
    int j = lane & 15, q = lane >> 4;
    int ka = tid >> 4, ra0 = tid & 15;
    int kb = tid & 15, rb0 = tid >> 4;
    int rowmap[4];
    mfma_rowmap(lane, rowmap);
    v4d acc[2][2];
#pragma unroll
    for (int fm = 0; fm < 2; fm++)
#pragma unroll
        for (int fn = 0; fn < 2; fn++)
#pragma unroll
            for (int i = 0; i < 4; i++) acc[fm][fn][i] = 0.0;

    for (int k0 = 0; k0 < 256; k0 += 16) {
#pragma unroll
        for (int rr = 0; rr < 4; rr++) {
            int ra = ra0 + rr * 16;
            int t = bm + ra; if (t > SSP - 1) t = SSP - 1;
            const float* sb; int hw, s;
            if (t < 10000)      { sb = s0; hw = 10000; s = t; }
            else if (t < 12500) { sb = s1; hw = 2500;  s = t - 10000; }
            else if (t < 13125) { sb = s2; hw = 625;   s = t - 12500; }
            else                { sb = s3; hw = 169;   s = t - 13125; }
            As[ka][ra] = (double)sb[(size_t)(b * 256 + k0 + ka) * hw + s];
            int rb = rb0 + rr * 16;
            Bs[kb][rb] = (double)W[(size_t)(c0 + rb) * 256 + k0 + kb];
        }
        __syncthreads();
#pragma unroll
        for (int kst = 0; kst < 4; kst++) {
            int krow = kst * 4 + q;
            double a0 = As[krow][wm + j];
            double a1 = As[krow][wm + 16 + j];
            double b0v = Bs[krow][wn + j];
            double b1v = Bs[krow][wn + 16 + j];
            acc[0][0] = __builtin_amdgcn_mfma_f64_16x16x4f64(a0, b0v, acc[0][0], 0, 0, 0);
            acc[0][1] = __builtin_amdgcn_mfma_f64_16x16x4f64(a0, b1v, acc[0][1], 0, 0, 0);
            acc[1][0] = __builtin_amdgcn_mfma_f64_16x16x4f64(a1, b0v, acc[1][0], 0, 0, 0);
            acc[1][1] = __builtin_amdgcn_mfma_f64_16x16x4f64(a1, b1v, acc[1][1], 0, 0, 0);
        }
        __syncthreads();
    }
#pragma unroll
    for (int fm = 0; fm < 2; fm++)
#pragma unroll
        for (int fn = 0; fn < 2; fn++)
#pragma unroll
            for (int i = 0; i < 4; i++) {
                int gm = bm + wm + fm * 16 + rowmap[i];
                int gn = wn + fn * 16 + j;
                if (gm < SSP)
                    outv[obase + (size_t)gm * 64 + gn] = (float)(acc[fm][fn][i] + (double)bias[c0 + gn]);
            }
}

// ------ K transpose for coalesced MHA QK reads: K_T[(b*8+h)*32+d][300] --------
__global__ __launch_bounds__(256)
void transpose_k(const float* __restrict__ qk, float* __restrict__ kt)
{
    int b = blockIdx.x >> 3, h = blockIdx.x & 7;
    __shared__ float tile[300][33];
    int tid = threadIdx.x;
    for (int e = tid; e < 300 * 32; e += 256) {
        int j = e >> 5, d = e & 31;
        tile[j][d] = qk[(size_t)(b * 300 + j) * 512 + 256 + h * 32 + d];
    }
    __syncthreads();
    size_t base = (size_t)(b * 8 + h) * 32 * 300;
    for (int e = tid; e < 32 * 300; e += 256) {
        int d = e / 300, j = e % 300;
        kt[base + (size_t)d * 300 + j] = tile[j][d];
    }
}

// ---------------- MHA, fp64 math, wave-parallel softmax -----------------------
__global__ __launch_bounds__(320)
void naive_mha(const float* __restrict__ qk, const float* __restrict__ kt,
               const float* __restrict__ vbuf, float* __restrict__ mha)
{
    int row = blockIdx.x;
    int b = row / 300;
    int h = blockIdx.y;
    const double scale = 0.17677669529663687;
    __shared__ double sc[304];
    __shared__ double red[8];
    __shared__ double ob[10][33];
    int j = threadIdx.x;
    double s = -1e300;
    if (j < 300) {
        const float* qp = qk + (size_t)row * 512 + h * 32;
        const float* ktp = kt + (size_t)(b * 8 + h) * 32 * 300 + j;
        double t = 0.;
#pragma unroll
        for (int d = 0; d < 32; d++) t += (double)qp[d] * (double)ktp[(size_t)d * 300];
        sc[j] = t; s = t;
    }
#pragma unroll
    for (int o = 32; o > 0; o >>= 1) s = fmax(s, __shfl_xor(s, o));
    int wv = j >> 6;
    if ((j & 63) == 0) red[wv] = s;
    __syncthreads();
    double mx = fmax(fmax(fmax(red[0], red[1]), fmax(red[2], red[3])), red[4]);
    double e = 0.;
    if (j < 300) { e = exp((sc[j] - mx) * scale); sc[j] = e; }
    double se = e;
#pragma unroll
    for (int o = 32; o > 0; o >>= 1) se += __shfl_xor(se, o);
    __syncthreads();
    if ((j & 63) == 0) red[wv] = se;
    __syncthreads();
    double inv = 1.0 / (red[0] + red[1] + red[2] + red[3] + red[4]);
    int d = j & 31, g = j >> 5;
    double o = 0.;
    const float* vp = vbuf + (size_t)(b * 300) * 256 + h * 32 + d;
    for (int t = g; t < 300; t += 10) o += sc[t] * (double)vp[(size_t)t * 256];
    ob[g][d] = o;
    __syncthreads();
    if (j < 32) {
        double acc2 = 0.;
#pragma unroll
        for (int g2 = 0; g2 < 10; g2++) acc2 += ob[g2][j];
        mha[(size_t)row * 256 + h * 32 + j] = (float)(acc2 * inv);
    }
}

// ---------------- small-N GEMMs, fp64 math ------------------------------------
__global__ __launch_bounds__(256)
void gemm_small_qe(const float* __restrict__ qe, const float* __restrict__ W,
                   const float* __restrict__ bias, float* __restrict__ out, int N, int M)
{
    int t = blockIdx.x * 256 + threadIdx.x;
    if (t >= M * N) return;
    int row = t / N, n = t % N;
    const float* a = qe + (size_t)(row % 300) * 512;
    const float* w = W + (size_t)n * 256;
    double s = 0.0;
    for (int k = 0; k < 256; k++) s += (double)a[k] * (double)w[k];
    out[t] = (float)(s + (double)bias[n]);
}
__global__ __launch_bounds__(256)
void gemm_smallN(const float* __restrict__ A, int lda, const float* __restrict__ W,
                 const float* __restrict__ bias, float* __restrict__ out, int N, int M)
{
    int t = blockIdx.x * 256 + threadIdx.x;
    if (t >= M * N) return;
    int row = t / N, n = t % N;
    const float* a = A + (size_t)row * lda;
    const float* w = W + (size_t)n * 256;
    double s = 0.0;
    for (int k = 0; k < 256; k++) s += (double)a[k] * (double)w[k];
    out[t] = (float)(s + (double)bias[n]);
}

// ---------------- tgt init (fp64 residual stream) -----------------------------
__global__ __launch_bounds__(256)
void init_tgt(const float* __restrict__ qe, double* __restrict__ tgt)
{
    int row = blockIdx.x, c = threadIdx.x;
    size_t i = (size_t)row * 256 + c;
    tgt[i] = (row < NROW) ? (double)qe[(size_t)(row % 300) * 512 + 256 + c] : 0.0;
}

__global__ void add_q(const double* __restrict__ tgt, const float* __restrict__ qe,
                      float* __restrict__ qin)
{
    int row = blockIdx.x, c = threadIdx.x;
    size_t i = (size_t)row * 256 + c;
    qin[i] = (float)(tgt[i] + (double)qe[(size_t)(row % 300) * 512 + c]);
}

// ---------------- fused residual-add + LayerNorm, fp64 math -------------------
__global__ __launch_bounds__(256)
void add_ln(double* __restrict__ tgt, const float* __restrict__ br,
            const float* __restrict__ w, const float* __restrict__ b,
            float* __restrict__ hs_out)
{
    int row = blockIdx.x, c = threadIdx.x;
    size_t idx = (size_t)row * 256 + c;
    double v = tgt[idx] + (double)br[idx];
    double s = v, s2 = v * v;
#pragma unroll
    for (int o = 32; o > 0; o >>= 1) { s += __shfl_xor(s, o); s2 += __shfl_xor(s2, o); }
    __shared__ double rs[4], rs2[4];
    int wv = c >> 6;
    if ((c & 63) == 0) { rs[wv] = s; rs2[wv] = s2; }
    __syncthreads();
    double S = rs[0] + rs[1] + rs[2] + rs[3];
    double S2 = rs2[0] + rs2[1] + rs2[2] + rs2[3];
    double mean = S * (1.0 / 256.0);
    double var = S2 * (1.0 / 256.0) - mean * mean;
    double o = (v - mean) / sqrt(var + 1e-5) * (double)w[c] + (double)b[c];
    tgt[idx] = o;
    if (hs_out) hs_out[idx] = (float)o;
}

// ---------------- attention-weight softmax over 16 per (row,h), fp64 ----------
__global__ __launch_bounds__(256)
void aw_softmax(float* __restrict__ buf)
{
    int t = blockIdx.x * 256 + threadIdx.x;
    if (t >= NROW * 8) return;
    int row = t >> 3, h = t & 7;
    float* p = buf + (size_t)row * 128 + h * 16;
    double mx = -1e300, e[16];
#pragma unroll
    for (int j = 0; j < 16; j++) mx = fmax(mx, (double)p[j]);
    double s = 0.;
#pragma unroll
    for (int j = 0; j < 16; j++) { e[j] = exp((double)p[j] - mx); s += e[j]; }
    double inv = 1.0 / s;
#pragma unroll
    for (int j = 0; j < 16; j++) p[j] = (float)(e[j] * inv);
}

// ------ deformable bilinear sampler; value holds 2 batches x 64 ch ------------
__global__ __launch_bounds__(64)
void deform_sample(const float* __restrict__ value, int h0,
                   const float* __restrict__ offb, const float* __restrict__ awsm,
                   const double* __restrict__ ref, float* __restrict__ out, int row0)
{
    int row = row0 + blockIdx.x;
    int hl = threadIdx.x >> 5, d = threadIdx.x & 31;
    int h = h0 + hl;
    double rx = ref[row * 4 + 0], ry = ref[row * 4 + 1];
    double rw = ref[row * 4 + 2], rh = ref[row * 4 + 3];
    const float* offr = offb + (size_t)row * 256;
    const float* awr = awsm + (size_t)row * 128 + h * 16;
    size_t vbase = (size_t)(blockIdx.x / 300) * SSP * 64 + hl * 32 + d;
    const int LH[4] = {100, 50, 25, 13};
    const int LW[4] = {100, 50, 25, 13};
    const int LS[4] = {0, 10000, 12500, 13125};
    double acc = 0.;
#pragma unroll
    for (int l = 0; l < 4; l++) {
        int Hh = LH[l], Ww = LW[l], st = LS[l];
#pragma unroll
        for (int p = 0; p < 4; p++) {
            double ox = (double)offr[(h * 32) + l * 8 + p * 2 + 0];
            double oy = (double)offr[(h * 32) + l * 8 + p * 2 + 1];
            double aw = (double)awr[l * 4 + p];
            double x = (rx + ox * 0.125 * rw) * Ww - 0.5;
            double y = (ry + oy * 0.125 * rh) * Hh - 0.5;
            double xf = floor(x), yf = floor(y);
            double dx = x - xf, dy = y - yf;
            int x0 = (int)xf, y0 = (int)yf;
            double w00 = (1 - dx) * (1 - dy), w10 = dx * (1 - dy);
            double w01 = (1 - dx) * dy, w11 = dx * dy;
#define CORN(X, Y, W)                                                              \
            if ((unsigned)(X) < (unsigned)Ww && (unsigned)(Y) < (unsigned)Hh)      \
                acc += (W) * aw * (double)value[vbase + (size_t)(st + (Y) * Ww + (X)) * 64];
            CORN(x0, y0, w00) CORN(x0 + 1, y0, w10) CORN(x0, y0 + 1, w01) CORN(x0 + 1, y0 + 1, w11)
#undef CORN
        }
    }
    out[(size_t)row * 256 + h * 32 + d] = (float)acc;
}

// ---------------- ref init / update (fp64 state, fp32 refs out) ---------------
__global__ void ref_init(const float* __restrict__ lin2, const float* __restrict__ bb,
                         double* __restrict__ ref)
{
    int t = blockIdx.x * 256 + threadIdx.x;
    if (t >= NROW) return;
#pragma unroll
    for (int j = 0; j < 2; j++) {
        double r2 = sigd((double)lin2[t * 2 + j]);
        ref[t * 4 + j] = sigd((double)bb[t * 4 + j] + invsigd(r2));
    }
    ref[t * 4 + 2] = sigd((double)bb[t * 4 + 2]);
    ref[t * 4 + 3] = sigd((double)bb[t * 4 + 3]);
}
__global__ void ref_update(const float* __restrict__ bb, double* __restrict__ ref,
                           float* __restrict__ refs_out)
{
    int t = blockIdx.x * 256 + threadIdx.x;
    if (t >= NROW * 4) return;
    double nv = sigd((double)bb[t] + invsigd(ref[t]));
    ref[t] = nv;
    refs_out[t] = (float)nv;
}

// =============================== launcher =====================================
extern "C" void kernel_launch(void* const* d_in, const int* in_sizes, int n_in,
                              void* d_out, int out_size, void* d_ws, size_t ws_size,
                              hipStream_t stream)
{
    const float* src0 = (const float*)d_in[0];
    const float* src1 = (const float*)d_in[2];
    const float* src2 = (const float*)d_in[4];
    const float* src3 = (const float*)d_in[6];
    const float* qe = (const float*)d_in[8];
    const float* ref_w = (const float*)d_in[9];
    const float* ref_b = (const float*)d_in[10];
    const float* sa_in_w = (const float*)d_in[11];
    const float* sa_in_b = (const float*)d_in[12];
    const float* sa_out_w = (const float*)d_in[13];
    const float* sa_out_b = (const float*)d_in[14];
    const float* off_w = (const float*)d_in[15];
    const float* off_b = (const float*)d_in[16];
    const float* aw_w = (const float*)d_in[17];
    const float* aw_b = (const float*)d_in[18];
    const float* val_w = (const float*)d_in[19];
    const float* val_b = (const float*)d_in[20];
    const float* cao_w = (const float*)d_in[21];
    const float* cao_b = (const float*)d_in[22];
    const float* ln1_w = (const float*)d_in[23];
    const float* ln1_b = (const float*)d_in[24];
    const float* ln2_w = (const float*)d_in[25];
    const float* ln2_b = (const float*)d_in[26];
    const float* ln3_w = (const float*)d_in[27];
    const float* ln3_b = (const float*)d_in[28];
    const float* ff1_w = (const float*)d_in[29];
    const float* ff1_b = (const float*)d_in[30];
    const float* ff2_w = (const float*)d_in[31];
    const float* ff2_b = (const float*)d_in[32];
    const float* bb_w1 = (const float*)d_in[33];
    const float* bb_b1 = (const float*)d_in[34];
    const float* bb_w2 = (const float*)d_in[35];
    const float* bb_b2 = (const float*)d_in[36];
    const float* bb_w3 = (const float*)d_in[37];
    const float* bb_b3 = (const float*)d_in[38];
    const float* cls_w = (const float*)d_in[39];
    const float* cls_b = (const float*)d_in[40];

    char* wsp = (char*)d_ws;
    size_t off_ws = 0;
    auto alloc = [&](size_t bytes) -> char* {
        char* p = wsp + off_ws;
        off_ws += (bytes + 255) & ~(size_t)255;
        return p;
    };
    // layout ~20.9 MB total (< 23 MB proven).
    // valueBig (2 batches x 64 ch = 6,806,528 B) = vhead ++ bufC (contiguous;
    // bufC is dead during the deform loop: qin/mha are self-attn/pre-deform,
    // bh2 is post-deform bbox).
    float* vhead = (float*)alloc(4316160);                   // 6,806,528-2,490,368
    char* bufC  = alloc((size_t)NROWP * 256 * 4);            // 2.49 union
    float* qin = (float*)bufC;
    float* mhab = (float*)bufC;
    float* bh2 = (float*)bufC;
    float* valueBig = vhead;                                 // spans vhead+bufC
    double* tgt  = (double*)alloc((size_t)NROWP * 256 * 8);  // 4.98 fp64 residual
    float* proj = (float*)alloc((size_t)NROWP * 256 * 4);    // 2.49 (also K_T: 2.46)
    char* bigA = alloc((size_t)NROWP * 512 * 4);             // 4.98 union
    float* qk   = (float*)bigA;
    float* ffnh = (float*)bigA;
    float* offb = (float*)bigA;
    float* awb  = (float*)(bigA + (size_t)NROWP * 256 * 4);
    char* bufB = alloc((size_t)NROWP * 256 * 4);             // 2.49 union
    float* vbuf = (float*)bufB;
    float* samp = (float*)bufB;
    float* bh1  = (float*)bufB;
    float* bb4   = (float*)alloc((size_t)NROWP * 4 * 4);
    double* refb = (double*)alloc((size_t)NROWP * 4 * 8);
    float* rlin2 = (float*)alloc((size_t)NROWP * 2 * 4);

    float* out_f = (float*)d_out;
    float* hs_out = out_f;                                   // 6 * 614400
    float* refs_out = out_f + (size_t)6 * 614400;            // 6 * 9600
    float* log_out = refs_out + (size_t)6 * 9600;            // 6 * 194400

    // ---- setup ----
    init_tgt<<<NROWP, 256, 0, stream>>>(qe, tgt);
    gemm_small_qe<<<(NROW * 2 + 255) / 256, 256, 0, stream>>>(qe, ref_w, ref_b, rlin2, 2, NROW);
    launch_m<double, true, false>(stream, tgt, 256, bb_w1, 256, bb_b1, bh1, 256, NROW, 256, 256);
    launch_m<float, true, false>(stream, bh1, 256, bb_w2, 256, bb_b2, proj, 256, NROW, 256, 256);
    gemm_smallN<<<(NROW * 4 + 255) / 256, 256, 0, stream>>>(proj, 256, bb_w3, bb_b3, bb4, 4, NROW);
    ref_init<<<(NROW + 255) / 256, 256, 0, stream>>>(rlin2, bb4, refb);

    for (int i = 0; i < 6; i++) {
        // ---- self attention ----
        add_q<<<NROW, 256, 0, stream>>>(tgt, qe, qin);
        launch_m<float, false, false>(stream, qin, 256, sa_in_w + (size_t)i * 196608, 256,
                                      sa_in_b + i * 768, qk, 512, NROW, 512, 256);
        launch_m<double, false, false>(stream, tgt, 256, sa_in_w + (size_t)i * 196608 + 131072, 256,
                                       sa_in_b + i * 768 + 512, vbuf, 256, NROW, 256, 256);
        transpose_k<<<64, 256, 0, stream>>>(qk, proj);
        naive_mha<<<dim3(NROW, 8), 320, 0, stream>>>(qk, proj, vbuf, mhab);
        launch_m<float, false, false>(stream, mhab, 256, sa_out_w + (size_t)i * 65536, 256,
                                      sa_out_b + i * 256, proj, 256, NROW, 256, 256);
        add_ln<<<NROW, 256, 0, stream>>>(tgt, proj, ln2_w + i * 256, ln2_b + i * 256, nullptr);

        // ---- deformable cross attention ----
        add_q<<<NROW, 256, 0, stream>>>(tgt, qe, qin);
        launch_m<float, false, false>(stream, qin, 256, off_w + (size_t)i * 65536, 256,
                                      off_b + i * 256, offb, 256, NROW, 256, 256);
        launch_m<float, false, false>(stream, qin, 256, aw_w + (size_t)i * 32768, 256,
                                      aw_b + i * 128, awb, 128, NROW, 128, 256);
        aw_softmax<<<(NROW * 8 + 255) / 256, 256, 0, stream>>>(awb);
        for (int s = 0; s < 4; s++) {
            for (int bg = 0; bg < 4; bg++) {
                value_mgemm<<<dim3((SSP + 63) / 64, 2), 256, 0, stream>>>(
                    src0, src1, src2, src3, bg * 2, val_w + (size_t)i * 65536, val_b + i * 256,
                    valueBig, s * 64);
                deform_sample<<<600, 64, 0, stream>>>(valueBig, s * 2, offb, awb, refb,
                                                      samp, bg * 600);
            }
        }
        launch_m<float, false, false>(stream, samp, 256, cao_w + (size_t)i * 65536, 256,
                                      cao_b + i * 256, proj, 256, NROW, 256, 256);
        add_ln<<<NROW, 256, 0, stream>>>(tgt, proj, ln1_w + i * 256, ln1_b + i * 256, nullptr);

        // ---- FFN, hidden split 2x512 into ffnh(bigA) ----
        launch_m<double, true, false>(stream, tgt, 256, ff1_w + (size_t)i * 262144, 256,
                                      ff1_b + i * 1024, ffnh, 512, NROW, 512, 256);
        launch_m<float, false, false>(stream, ffnh, 512, ff2_w + (size_t)i * 262144, 1024,
                                      ff2_b + i * 256, proj, 256, NROW, 256, 512);
        launch_m<double, true, false>(stream, tgt, 256, ff1_w + (size_t)i * 262144 + 512 * 256, 256,
                                      ff1_b + i * 1024 + 512, ffnh, 512, NROW, 512, 256);
        launch_m<float, false, true>(stream, ffnh, 512, ff2_w + (size_t)i * 262144 + 512, 1024,
                                     nullptr, proj, 256, NROW, 256, 512);
        add_ln<<<NROW, 256, 0, stream>>>(tgt, proj, ln3_w + i * 256, ln3_b + i * 256,
                                         hs_out + (size_t)i * 614400);

        // ---- bbox refinement: bh1(bufB), bh2(bufC) ----
        launch_m<double, true, false>(stream, tgt, 256, bb_w1 + (size_t)(i + 1) * 65536, 256,
                                      bb_b1 + (i + 1) * 256, bh1, 256, NROW, 256, 256);
        launch_m<float, true, false>(stream, bh1, 256, bb_w2 + (size_t)(i + 1) * 65536, 256,
                                     bb_b2 + (i + 1) * 256, bh2, 256, NROW, 256, 256);
        gemm_smallN<<<(NROW * 4 + 255) / 256, 256, 0, stream>>>(
            bh2, 256, bb_w3 + (size_t)(i + 1) * 1024, bb_b3 + (i + 1) * 4, bb4, 4, NROW);
        ref_update<<<(NROW * 4 + 255) / 256, 256, 0, stream>>>(bb4, refb, refs_out + (size_t)i * 9600);

        // ---- logits ----
        launch_m<double, false, false>(stream, tgt, 256, cls_w + (size_t)(i + 1) * 20736, 256,
                                       cls_b + (i + 1) * 81, log_out + (size_t)i * 194400,
                                       81, NROW, 81, 256);
    }
}

// Round 4
// 6342.928 us; speedup vs baseline: 2.8645x; 1.2845x over previous
//
#include <hip/hip_runtime.h>
#include <cstdint>

#define SSP   13294      // total spatial tokens (100^2+50^2+25^2+13^2)
#define NROW  2400       // B*NQ
#define NROWP 2432

typedef double v4d __attribute__((ext_vector_type(4)));

__device__ __forceinline__ double sigd(double x) { return 1.0 / (1.0 + exp(-x)); }
__device__ __forceinline__ double invsigd(double x) {
    x = fmin(fmax(x, 0.0), 1.0);
    return log(fmax(x, 1e-5) / fmax(1.0 - x, 1e-5));
}
__device__ __forceinline__ double rdA(const float* a, size_t k) { return (double)a[k]; }
__device__ __forceinline__ double rdA(const double* a, size_t k) { return a[k]; }

// Self-calibrating probe for the f64 MFMA C/D row mapping (verified working r2).
__device__ __forceinline__ void mfma_rowmap(int lane, int* rm) {
    v4d c = {0., 0., 0., 0.};
    double a = (double)(lane & 15);
    c = __builtin_amdgcn_mfma_f64_16x16x4f64(a, 0.25, c, 0, 0, 0);
#pragma unroll
    for (int r = 0; r < 4; r++) rm[r] = (int)(c[r] + 0.5);
}

// ---- fp64 MFMA GEMM: C (+)= relu?(A(MxK) @ W(NxK)^T + bias) -----------------
template<typename TA, bool RELU, bool ACC>
__global__ __launch_bounds__(256)
void mgemm(const TA* __restrict__ A, int lda,
           const float* __restrict__ W, int ldb,
           const float* __restrict__ bias,
           float* __restrict__ C, int ldc,
           int M, int N, int K)
{
    __shared__ double As[16][66];
    __shared__ double Bs[16][66];
    int bm = blockIdx.x * 64, bn = blockIdx.y * 64;
    int tid = threadIdx.x;
    int lane = tid & 63, wave = tid >> 6;
    int wm = (wave >> 1) * 32, wn = (wave & 1) * 32;
    int j = lane & 15, q = lane >> 4;
    int kk = tid & 15, r0 = tid >> 4;
    int rowmap[4];
    mfma_rowmap(lane, rowmap);
    v4d acc[2][2];
#pragma unroll
    for (int fm = 0; fm < 2; fm++)
#pragma unroll
        for (int fn = 0; fn < 2; fn++)
#pragma unroll
            for (int i = 0; i < 4; i++) acc[fm][fn][i] = 0.0;

    for (int k0 = 0; k0 < K; k0 += 16) {
#pragma unroll
        for (int rr = 0; rr < 4; rr++) {
            int r = r0 + rr * 16;
            int am = bm + r; if (am > M - 1) am = M - 1;
            As[kk][r] = rdA(A, (size_t)am * lda + k0 + kk);
            int wn_ = bn + r; if (wn_ > N - 1) wn_ = N - 1;
            Bs[kk][r] = (double)W[(size_t)wn_ * ldb + k0 + kk];
        }
        __syncthreads();
#pragma unroll
        for (int kst = 0; kst < 4; kst++) {
            int krow = kst * 4 + q;
            double a0 = As[krow][wm + j];
            double a1 = As[krow][wm + 16 + j];
            double b0 = Bs[krow][wn + j];
            double b1 = Bs[krow][wn + 16 + j];
            acc[0][0] = __builtin_amdgcn_mfma_f64_16x16x4f64(a0, b0, acc[0][0], 0, 0, 0);
            acc[0][1] = __builtin_amdgcn_mfma_f64_16x16x4f64(a0, b1, acc[0][1], 0, 0, 0);
            acc[1][0] = __builtin_amdgcn_mfma_f64_16x16x4f64(a1, b0, acc[1][0], 0, 0, 0);
            acc[1][1] = __builtin_amdgcn_mfma_f64_16x16x4f64(a1, b1, acc[1][1], 0, 0, 0);
        }
        __syncthreads();
    }
#pragma unroll
    for (int fm = 0; fm < 2; fm++)
#pragma unroll
        for (int fn = 0; fn < 2; fn++)
#pragma unroll
            for (int i = 0; i < 4; i++) {
                int gm = bm + wm + fm * 16 + rowmap[i];
                int gn = bn + wn + fn * 16 + j;
                if (gm < M && gn < N) {
                    double v = acc[fm][fn][i] + (bias ? (double)bias[gn] : 0.0);
                    if (ACC) v += (double)C[(size_t)gm * ldc + gn];
                    if (RELU) v = fmax(v, 0.0);
                    C[(size_t)gm * ldc + gn] = (float)v;
                }
            }
}

template<typename TA, bool RELU, bool ACC>
static void launch_m(hipStream_t st, const TA* A, int lda, const float* W, int ldb,
                     const float* bias, float* C, int ldc, int M, int N, int K)
{
    dim3 grid((M + 63) / 64, (N + 63) / 64, 1);
    mgemm<TA, RELU, ACC><<<grid, 256, 0, st>>>(A, lda, W, ldb, bias, C, ldc, M, N, K);
}

// -- OLD value GEMM (fallback), 64-ch slice, 2 batches -------------------------
__global__ __launch_bounds__(256)
void value_mgemm(const float* __restrict__ s0, const float* __restrict__ s1,
                 const float* __restrict__ s2, const float* __restrict__ s3,
                 int b0, const float* __restrict__ W, const float* __restrict__ bias,
                 float* __restrict__ outv, int c0)
{
    __shared__ double As[16][66];
    __shared__ double Bs[16][66];
    int bm = blockIdx.x * 64;
    int b = b0 + blockIdx.y;
    size_t obase = (size_t)blockIdx.y * SSP * 64;
    int tid = threadIdx.x;
    int lane = tid & 63, wave = tid >> 6;
    int wm = (wave >> 1) * 32, wn = (wave & 1) * 32;
    int j = lane & 15, q = lane >> 4;
    int ka = tid >> 4, ra0 = tid & 15;
    int kb = tid & 15, rb0 = tid >> 4;
    int rowmap[4];
    mfma_rowmap(lane, rowmap);
    v4d acc[2][2];
#pragma unroll
    for (int fm = 0; fm < 2; fm++)
#pragma unroll
        for (int fn = 0; fn < 2; fn++)
#pragma unroll
            for (int i = 0; i < 4; i++) acc[fm][fn][i] = 0.0;

    for (int k0 = 0; k0 < 256; k0 += 16) {
#pragma unroll
        for (int rr = 0; rr < 4; rr++) {
            int ra = ra0 + rr * 16;
            int t = bm + ra; if (t > SSP - 1) t = SSP - 1;
            const float* sb; int hw, s;
            if (t < 10000)      { sb = s0; hw = 10000; s = t; }
            else if (t < 12500) { sb = s1; hw = 2500;  s = t - 10000; }
            else if (t < 13125) { sb = s2; hw = 625;   s = t - 12500; }
            else                { sb = s3; hw = 169;   s = t - 13125; }
            As[ka][ra] = (double)sb[(size_t)(b * 256 + k0 + ka) * hw + s];
            int rb = rb0 + rr * 16;
            Bs[kb][rb] = (double)W[(size_t)(c0 + rb) * 256 + k0 + kb];
        }
        __syncthreads();
#pragma unroll
        for (int kst = 0; kst < 4; kst++) {
            int krow = kst * 4 + q;
            double a0 = As[krow][wm + j];
            double a1 = As[krow][wm + 16 + j];
            double b0v = Bs[krow][wn + j];
            double b1v = Bs[krow][wn + 16 + j];
            acc[0][0] = __builtin_amdgcn_mfma_f64_16x16x4f64(a0, b0v, acc[0][0], 0, 0, 0);
            acc[0][1] = __builtin_amdgcn_mfma_f64_16x16x4f64(a0, b1v, acc[0][1], 0, 0, 0);
            acc[1][0] = __builtin_amdgcn_mfma_f64_16x16x4f64(a1, b0v, acc[1][0], 0, 0, 0);
            acc[1][1] = __builtin_amdgcn_mfma_f64_16x16x4f64(a1, b1v, acc[1][1], 0, 0, 0);
        }
        __syncthreads();
    }
#pragma unroll
    for (int fm = 0; fm < 2; fm++)
#pragma unroll
        for (int fn = 0; fn < 2; fn++)
#pragma unroll
            for (int i = 0; i < 4; i++) {
                int gm = bm + wm + fm * 16 + rowmap[i];
                int gn = wn + fn * 16 + j;
                if (gm < SSP)
                    outv[obase + (size_t)gm * 64 + gn] = (float)(acc[fm][fn][i] + (double)bias[c0 + gn]);
            }
}

// -- NEW value GEMM: full 256 ch, nb batches; BM=128/BN=64, grid(104,4,nb) -----
__global__ __launch_bounds__(256)
void value2_mgemm(const float* __restrict__ s0, const float* __restrict__ s1,
                  const float* __restrict__ s2, const float* __restrict__ s3,
                  int b0, const float* __restrict__ W, const float* __restrict__ bias,
                  float* __restrict__ outv)
{
    __shared__ double As[16][130];
    __shared__ double Bs[16][66];
    int bm = blockIdx.x * 128;
    int bn = blockIdx.y * 64;
    int b = b0 + blockIdx.z;
    size_t obase = (size_t)blockIdx.z * SSP * 256;
    int tid = threadIdx.x;
    int lane = tid & 63, wave = tid >> 6;
    int wm = (wave >> 1) * 64, wn = (wave & 1) * 32;
    int j = lane & 15, q = lane >> 4;
    int ka = tid >> 4, ra0 = tid & 15;
    int kb = tid & 15, rb0 = tid >> 4;
    int rowmap[4];
    mfma_rowmap(lane, rowmap);
    v4d acc[4][2];
#pragma unroll
    for (int fm = 0; fm < 4; fm++)
#pragma unroll
        for (int fn = 0; fn < 2; fn++)
#pragma unroll
            for (int i = 0; i < 4; i++) acc[fm][fn][i] = 0.0;

    for (int k0 = 0; k0 < 256; k0 += 16) {
#pragma unroll
        for (int rr = 0; rr < 8; rr++) {
            int ra = ra0 + rr * 16;
            int t = bm + ra; if (t > SSP - 1) t = SSP - 1;
            const float* sb; int hw, s;
            if (t < 10000)      { sb = s0; hw = 10000; s = t; }
            else if (t < 12500) { sb = s1; hw = 2500;  s = t - 10000; }
            else if (t < 13125) { sb = s2; hw = 625;   s = t - 12500; }
            else                { sb = s3; hw = 169;   s = t - 13125; }
            As[ka][ra] = (double)sb[(size_t)(b * 256 + k0 + ka) * hw + s];
        }
#pragma unroll
        for (int rr = 0; rr < 4; rr++) {
            int rb = rb0 + rr * 16;
            Bs[kb][rb] = (double)W[(size_t)(bn + rb) * 256 + k0 + kb];
        }
        __syncthreads();
#pragma unroll
        for (int kst = 0; kst < 4; kst++) {
            int krow = kst * 4 + q;
            double a0 = As[krow][wm + j];
            double a1 = As[krow][wm + 16 + j];
            double a2 = As[krow][wm + 32 + j];
            double a3 = As[krow][wm + 48 + j];
            double b0v = Bs[krow][wn + j];
            double b1v = Bs[krow][wn + 16 + j];
            acc[0][0] = __builtin_amdgcn_mfma_f64_16x16x4f64(a0, b0v, acc[0][0], 0, 0, 0);
            acc[0][1] = __builtin_amdgcn_mfma_f64_16x16x4f64(a0, b1v, acc[0][1], 0, 0, 0);
            acc[1][0] = __builtin_amdgcn_mfma_f64_16x16x4f64(a1, b0v, acc[1][0], 0, 0, 0);
            acc[1][1] = __builtin_amdgcn_mfma_f64_16x16x4f64(a1, b1v, acc[1][1], 0, 0, 0);
            acc[2][0] = __builtin_amdgcn_mfma_f64_16x16x4f64(a2, b0v, acc[2][0], 0, 0, 0);
            acc[2][1] = __builtin_amdgcn_mfma_f64_16x16x4f64(a2, b1v, acc[2][1], 0, 0, 0);
            acc[3][0] = __builtin_amdgcn_mfma_f64_16x16x4f64(a3, b0v, acc[3][0], 0, 0, 0);
            acc[3][1] = __builtin_amdgcn_mfma_f64_16x16x4f64(a3, b1v, acc[3][1], 0, 0, 0);
        }
        __syncthreads();
    }
#pragma unroll
    for (int fm = 0; fm < 4; fm++)
#pragma unroll
        for (int fn = 0; fn < 2; fn++)
#pragma unroll
            for (int i = 0; i < 4; i++) {
                int gm = bm + wm + fm * 16 + rowmap[i];
                int gn = bn + wn + fn * 16 + j;
                if (gm < SSP)
                    outv[obase + (size_t)gm * 256 + gn] = (float)(acc[fm][fn][i] + (double)bias[gn]);
            }
}

// ------ K transpose for coalesced MHA QK reads: K_T[(b*8+h)*32+d][300] --------
__global__ __launch_bounds__(256)
void transpose_k(const float* __restrict__ qk, float* __restrict__ kt)
{
    int b = blockIdx.x >> 3, h = blockIdx.x & 7;
    __shared__ float tile[300][33];
    int tid = threadIdx.x;
    for (int e = tid; e < 300 * 32; e += 256) {
        int j = e >> 5, d = e & 31;
        tile[j][d] = qk[(size_t)(b * 300 + j) * 512 + 256 + h * 32 + d];
    }
    __syncthreads();
    size_t base = (size_t)(b * 8 + h) * 32 * 300;
    for (int e = tid; e < 32 * 300; e += 256) {
        int d = e / 300, j = e % 300;
        kt[base + (size_t)d * 300 + j] = tile[j][d];
    }
}

// ---------------- MHA, fp64 math, wave-parallel softmax -----------------------
__global__ __launch_bounds__(320)
void naive_mha(const float* __restrict__ qk, const float* __restrict__ kt,
               const float* __restrict__ vbuf, float* __restrict__ mha)
{
    int row = blockIdx.x;
    int b = row / 300;
    int h = blockIdx.y;
    const double scale = 0.17677669529663687;
    __shared__ double sc[304];
    __shared__ double red[8];
    __shared__ double ob[10][33];
    int j = threadIdx.x;
    double s = -1e300;
    if (j < 300) {
        const float* qp = qk + (size_t)row * 512 + h * 32;
        const float* ktp = kt + (size_t)(b * 8 + h) * 32 * 300 + j;
        double t = 0.;
#pragma unroll
        for (int d = 0; d < 32; d++) t += (double)qp[d] * (double)ktp[(size_t)d * 300];
        sc[j] = t; s = t;
    }
#pragma unroll
    for (int o = 32; o > 0; o >>= 1) s = fmax(s, __shfl_xor(s, o));
    int wv = j >> 6;
    if ((j & 63) == 0) red[wv] = s;
    __syncthreads();
    double mx = fmax(fmax(fmax(red[0], red[1]), fmax(red[2], red[3])), red[4]);
    double e = 0.;
    if (j < 300) { e = exp((sc[j] - mx) * scale); sc[j] = e; }
    double se = e;
#pragma unroll
    for (int o = 32; o > 0; o >>= 1) se += __shfl_xor(se, o);
    __syncthreads();
    if ((j & 63) == 0) red[wv] = se;
    __syncthreads();
    double inv = 1.0 / (red[0] + red[1] + red[2] + red[3] + red[4]);
    int d = j & 31, g = j >> 5;
    double o = 0.;
    const float* vp = vbuf + (size_t)(b * 300) * 256 + h * 32 + d;
    for (int t = g; t < 300; t += 10) o += sc[t] * (double)vp[(size_t)t * 256];
    ob[g][d] = o;
    __syncthreads();
    if (j < 32) {
        double acc2 = 0.;
#pragma unroll
        for (int g2 = 0; g2 < 10; g2++) acc2 += ob[g2][j];
        mha[(size_t)row * 256 + h * 32 + j] = (float)(acc2 * inv);
    }
}

// ---------------- small-N GEMMs, fp64 math ------------------------------------
__global__ __launch_bounds__(256)
void gemm_small_qe(const float* __restrict__ qe, const float* __restrict__ W,
                   const float* __restrict__ bias, float* __restrict__ out, int N, int M)
{
    int t = blockIdx.x * 256 + threadIdx.x;
    if (t >= M * N) return;
    int row = t / N, n = t % N;
    const float* a = qe + (size_t)(row % 300) * 512;
    const float* w = W + (size_t)n * 256;
    double s = 0.0;
    for (int k = 0; k < 256; k++) s += (double)a[k] * (double)w[k];
    out[t] = (float)(s + (double)bias[n]);
}
__global__ __launch_bounds__(256)
void gemm_smallN(const float* __restrict__ A, int lda, const float* __restrict__ W,
                 const float* __restrict__ bias, float* __restrict__ out, int N, int M)
{
    int t = blockIdx.x * 256 + threadIdx.x;
    if (t >= M * N) return;
    int row = t / N, n = t % N;
    const float* a = A + (size_t)row * lda;
    const float* w = W + (size_t)n * 256;
    double s = 0.0;
    for (int k = 0; k < 256; k++) s += (double)a[k] * (double)w[k];
    out[t] = (float)(s + (double)bias[n]);
}

// ---------------- tgt init (fp64 residual stream) -----------------------------
__global__ __launch_bounds__(256)
void init_tgt(const float* __restrict__ qe, double* __restrict__ tgt)
{
    int row = blockIdx.x, c = threadIdx.x;
    size_t i = (size_t)row * 256 + c;
    tgt[i] = (row < NROW) ? (double)qe[(size_t)(row % 300) * 512 + 256 + c] : 0.0;
}

__global__ void add_q(const double* __restrict__ tgt, const float* __restrict__ qe,
                      float* __restrict__ qin)
{
    int row = blockIdx.x, c = threadIdx.x;
    size_t i = (size_t)row * 256 + c;
    qin[i] = (float)(tgt[i] + (double)qe[(size_t)(row % 300) * 512 + c]);
}

// ---------------- fused residual-add + LayerNorm, fp64 math -------------------
__global__ __launch_bounds__(256)
void add_ln(double* __restrict__ tgt, const float* __restrict__ br,
            const float* __restrict__ w, const float* __restrict__ b,
            float* __restrict__ hs_out)
{
    int row = blockIdx.x, c = threadIdx.x;
    size_t idx = (size_t)row * 256 + c;
    double v = tgt[idx] + (double)br[idx];
    double s = v, s2 = v * v;
#pragma unroll
    for (int o = 32; o > 0; o >>= 1) { s += __shfl_xor(s, o); s2 += __shfl_xor(s2, o); }
    __shared__ double rs[4], rs2[4];
    int wv = c >> 6;
    if ((c & 63) == 0) { rs[wv] = s; rs2[wv] = s2; }
    __syncthreads();
    double S = rs[0] + rs[1] + rs[2] + rs[3];
    double S2 = rs2[0] + rs2[1] + rs2[2] + rs2[3];
    double mean = S * (1.0 / 256.0);
    double var = S2 * (1.0 / 256.0) - mean * mean;
    double o = (v - mean) / sqrt(var + 1e-5) * (double)w[c] + (double)b[c];
    tgt[idx] = o;
    if (hs_out) hs_out[idx] = (float)o;
}

// ---------------- attention-weight softmax over 16 per (row,h), fp64 ----------
__global__ __launch_bounds__(256)
void aw_softmax(float* __restrict__ buf)
{
    int t = blockIdx.x * 256 + threadIdx.x;
    if (t >= NROW * 8) return;
    int row = t >> 3, h = t & 7;
    float* p = buf + (size_t)row * 128 + h * 16;
    double mx = -1e300, e[16];
#pragma unroll
    for (int j = 0; j < 16; j++) mx = fmax(mx, (double)p[j]);
    double s = 0.;
#pragma unroll
    for (int j = 0; j < 16; j++) { e[j] = exp((double)p[j] - mx); s += e[j]; }
    double inv = 1.0 / s;
#pragma unroll
    for (int j = 0; j < 16; j++) p[j] = (float)(e[j] * inv);
}

// ------ OLD sampler (fallback): value 2 batches x 64 ch slice -----------------
__global__ __launch_bounds__(64)
void deform_sample(const float* __restrict__ value, int h0,
                   const float* __restrict__ offb, const float* __restrict__ awsm,
                   const double* __restrict__ ref, float* __restrict__ out, int row0)
{
    int row = row0 + blockIdx.x;
    int hl = threadIdx.x >> 5, d = threadIdx.x & 31;
    int h = h0 + hl;
    double rx = ref[row * 4 + 0], ry = ref[row * 4 + 1];
    double rw = ref[row * 4 + 2], rh = ref[row * 4 + 3];
    const float* offr = offb + (size_t)row * 256;
    const float* awr = awsm + (size_t)row * 128 + h * 16;
    size_t vbase = (size_t)(blockIdx.x / 300) * SSP * 64 + hl * 32 + d;
    const int LH[4] = {100, 50, 25, 13};
    const int LW[4] = {100, 50, 25, 13};
    const int LS[4] = {0, 10000, 12500, 13125};
    double acc = 0.;
#pragma unroll
    for (int l = 0; l < 4; l++) {
        int Hh = LH[l], Ww = LW[l], st = LS[l];
#pragma unroll
        for (int p = 0; p < 4; p++) {
            double ox = (double)offr[(h * 32) + l * 8 + p * 2 + 0];
            double oy = (double)offr[(h * 32) + l * 8 + p * 2 + 1];
            double aw = (double)awr[l * 4 + p];
            double x = (rx + ox * 0.125 * rw) * Ww - 0.5;
            double y = (ry + oy * 0.125 * rh) * Hh - 0.5;
            double xf = floor(x), yf = floor(y);
            double dx = x - xf, dy = y - yf;
            int x0 = (int)xf, y0 = (int)yf;
            double w00 = (1 - dx) * (1 - dy), w10 = dx * (1 - dy);
            double w01 = (1 - dx) * dy, w11 = dx * dy;
#define CORN(X, Y, W)                                                              \
            if ((unsigned)(X) < (unsigned)Ww && (unsigned)(Y) < (unsigned)Hh)      \
                acc += (W) * aw * (double)value[vbase + (size_t)(st + (Y) * Ww + (X)) * 64];
            CORN(x0, y0, w00) CORN(x0 + 1, y0, w10) CORN(x0, y0 + 1, w01) CORN(x0 + 1, y0 + 1, w11)
#undef CORN
        }
    }
    out[(size_t)row * 256 + h * 32 + d] = (float)acc;
}

// ------ NEW sampler: value [bslot][token][256], all 8 heads per block ---------
__global__ __launch_bounds__(256)
void deform_sample2(const float* __restrict__ value,
                    const float* __restrict__ offb, const float* __restrict__ awsm,
                    const double* __restrict__ ref, float* __restrict__ out, int row0)
{
    int row = row0 + blockIdx.x;
    int h = threadIdx.x >> 5, d = threadIdx.x & 31;
    double rx = ref[row * 4 + 0], ry = ref[row * 4 + 1];
    double rw = ref[row * 4 + 2], rh = ref[row * 4 + 3];
    const float* offr = offb + (size_t)row * 256;
    const float* awr = awsm + (size_t)row * 128 + h * 16;
    size_t vbase = (size_t)(blockIdx.x / 300) * SSP * 256 + h * 32 + d;
    const int LH[4] = {100, 50, 25, 13};
    const int LW[4] = {100, 50, 25, 13};
    const int LS[4] = {0, 10000, 12500, 13125};
    double acc = 0.;
#pragma unroll
    for (int l = 0; l < 4; l++) {
        int Hh = LH[l], Ww = LW[l], st = LS[l];
#pragma unroll
        for (int p = 0; p < 4; p++) {
            double ox = (double)offr[(h * 32) + l * 8 + p * 2 + 0];
            double oy = (double)offr[(h * 32) + l * 8 + p * 2 + 1];
            double aw = (double)awr[l * 4 + p];
            double x = (rx + ox * 0.125 * rw) * Ww - 0.5;
            double y = (ry + oy * 0.125 * rh) * Hh - 0.5;
            double xf = floor(x), yf = floor(y);
            double dx = x - xf, dy = y - yf;
            int x0 = (int)xf, y0 = (int)yf;
            double w00 = (1 - dx) * (1 - dy), w10 = dx * (1 - dy);
            double w01 = (1 - dx) * dy, w11 = dx * dy;
#define CORN(X, Y, W)                                                              \
            if ((unsigned)(X) < (unsigned)Ww && (unsigned)(Y) < (unsigned)Hh)      \
                acc += (W) * aw * (double)value[vbase + (size_t)(st + (Y) * Ww + (X)) * 256];
            CORN(x0, y0, w00) CORN(x0 + 1, y0, w10) CORN(x0, y0 + 1, w01) CORN(x0 + 1, y0 + 1, w11)
#undef CORN
        }
    }
    out[(size_t)row * 256 + h * 32 + d] = (float)acc;
}

// ---------------- ref init / update (fp64 state, fp32 refs out) ---------------
__global__ void ref_init(const float* __restrict__ lin2, const float* __restrict__ bb,
                         double* __restrict__ ref)
{
    int t = blockIdx.x * 256 + threadIdx.x;
    if (t >= NROW) return;
#pragma unroll
    for (int j = 0; j < 2; j++) {
        double r2 = sigd((double)lin2[t * 2 + j]);
        ref[t * 4 + j] = sigd((double)bb[t * 4 + j] + invsigd(r2));
    }
    ref[t * 4 + 2] = sigd((double)bb[t * 4 + 2]);
    ref[t * 4 + 3] = sigd((double)bb[t * 4 + 3]);
}
__global__ void ref_update(const float* __restrict__ bb, double* __restrict__ ref,
                           float* __restrict__ refs_out)
{
    int t = blockIdx.x * 256 + threadIdx.x;
    if (t >= NROW * 4) return;
    double nv = sigd((double)bb[t] + invsigd(ref[t]));
    ref[t] = nv;
    refs_out[t] = (float)nv;
}

// =============================== launcher =====================================
extern "C" void kernel_launch(void* const* d_in, const int* in_sizes, int n_in,
                              void* d_out, int out_size, void* d_ws, size_t ws_size,
                              hipStream_t stream)
{
    const float* src0 = (const float*)d_in[0];
    const float* src1 = (const float*)d_in[2];
    const float* src2 = (const float*)d_in[4];
    const float* src3 = (const float*)d_in[6];
    const float* qe = (const float*)d_in[8];
    const float* ref_w = (const float*)d_in[9];
    const float* ref_b = (const float*)d_in[10];
    const float* sa_in_w = (const float*)d_in[11];
    const float* sa_in_b = (const float*)d_in[12];
    const float* sa_out_w = (const float*)d_in[13];
    const float* sa_out_b = (const float*)d_in[14];
    const float* off_w = (const float*)d_in[15];
    const float* off_b = (const float*)d_in[16];
    const float* aw_w = (const float*)d_in[17];
    const float* aw_b = (const float*)d_in[18];
    const float* val_w = (const float*)d_in[19];
    const float* val_b = (const float*)d_in[20];
    const float* cao_w = (const float*)d_in[21];
    const float* cao_b = (const float*)d_in[22];
    const float* ln1_w = (const float*)d_in[23];
    const float* ln1_b = (const float*)d_in[24];
    const float* ln2_w = (const float*)d_in[25];
    const float* ln2_b = (const float*)d_in[26];
    const float* ln3_w = (const float*)d_in[27];
    const float* ln3_b = (const float*)d_in[28];
    const float* ff1_w = (const float*)d_in[29];
    const float* ff1_b = (const float*)d_in[30];
    const float* ff2_w = (const float*)d_in[31];
    const float* ff2_b = (const float*)d_in[32];
    const float* bb_w1 = (const float*)d_in[33];
    const float* bb_b1 = (const float*)d_in[34];
    const float* bb_w2 = (const float*)d_in[35];
    const float* bb_b2 = (const float*)d_in[36];
    const float* bb_w3 = (const float*)d_in[37];
    const float* bb_b3 = (const float*)d_in[38];
    const float* cls_w = (const float*)d_in[39];
    const float* cls_b = (const float*)d_in[40];

    char* wsp = (char*)d_ws;
    size_t off_ws = 0;
    auto alloc = [&](size_t bytes) -> char* {
        char* p = wsp + off_ws;
        off_ws += (bytes + 255) & ~(size_t)255;
        return p;
    };
    // unified layout: fixed buffers first, then proj/bufC, then open-ended value
    // region starting at proj (proj and bufC are dead during the deform loop).
    double* tgt  = (double*)alloc((size_t)NROWP * 256 * 8);  // 4.98 MB fp64 residual
    char* bigA = alloc((size_t)NROWP * 512 * 4);             // 4.98 union
    float* qk   = (float*)bigA;
    float* ffnh = (float*)bigA;
    float* offb = (float*)bigA;
    float* awb  = (float*)(bigA + (size_t)NROWP * 256 * 4);
    char* bufB = alloc((size_t)NROWP * 256 * 4);             // 2.49 union
    float* vbuf = (float*)bufB;
    float* samp = (float*)bufB;
    float* bh1  = (float*)bufB;
    float* bb4   = (float*)alloc((size_t)NROWP * 4 * 4);
    double* refb = (double*)alloc((size_t)NROWP * 4 * 8);
    float* rlin2 = (float*)alloc((size_t)NROWP * 2 * 4);
    size_t val_off = off_ws;
    float* proj = (float*)alloc((size_t)NROWP * 256 * 4);    // 2.49 (also K_T)
    char* bufC  = alloc((size_t)NROWP * 256 * 4);            // 2.49 union
    float* qin = (float*)bufC;
    float* mhab = (float*)bufC;
    float* bh2 = (float*)bufC;
    float* valueBig = proj;   // value region spans proj, bufC, and ws tail

    // path selection by available workspace beyond val_off
    size_t avail = ws_size > val_off ? ws_size - val_off : 0;
    int nb = 0;               // batches of full-256ch value held at once
    if (avail >= (size_t)2 * SSP * 256 * 4 + 4096) nb = 2;
    else if (avail >= (size_t)SSP * 256 * 4 + 4096) nb = 1;
    // nb==0 -> fallback 64-ch-slice path (needs 6.81 MB at val_off, proven safe)

    float* out_f = (float*)d_out;
    float* hs_out = out_f;                                   // 6 * 614400
    float* refs_out = out_f + (size_t)6 * 614400;            // 6 * 9600
    float* log_out = refs_out + (size_t)6 * 9600;            // 6 * 194400

    // ---- setup ----
    init_tgt<<<NROWP, 256, 0, stream>>>(qe, tgt);
    gemm_small_qe<<<(NROW * 2 + 255) / 256, 256, 0, stream>>>(qe, ref_w, ref_b, rlin2, 2, NROW);
    launch_m<double, true, false>(stream, tgt, 256, bb_w1, 256, bb_b1, bh1, 256, NROW, 256, 256);
    launch_m<float, true, false>(stream, bh1, 256, bb_w2, 256, bb_b2, proj, 256, NROW, 256, 256);
    gemm_smallN<<<(NROW * 4 + 255) / 256, 256, 0, stream>>>(proj, 256, bb_w3, bb_b3, bb4, 4, NROW);
    ref_init<<<(NROW + 255) / 256, 256, 0, stream>>>(rlin2, bb4, refb);

    for (int i = 0; i < 6; i++) {
        // ---- self attention ----
        add_q<<<NROW, 256, 0, stream>>>(tgt, qe, qin);
        launch_m<float, false, false>(stream, qin, 256, sa_in_w + (size_t)i * 196608, 256,
                                      sa_in_b + i * 768, qk, 512, NROW, 512, 256);
        launch_m<double, false, false>(stream, tgt, 256, sa_in_w + (size_t)i * 196608 + 131072, 256,
                                       sa_in_b + i * 768 + 512, vbuf, 256, NROW, 256, 256);
        transpose_k<<<64, 256, 0, stream>>>(qk, proj);
        naive_mha<<<dim3(NROW, 8), 320, 0, stream>>>(qk, proj, vbuf, mhab);
        launch_m<float, false, false>(stream, mhab, 256, sa_out_w + (size_t)i * 65536, 256,
                                      sa_out_b + i * 256, proj, 256, NROW, 256, 256);
        add_ln<<<NROW, 256, 0, stream>>>(tgt, proj, ln2_w + i * 256, ln2_b + i * 256, nullptr);

        // ---- deformable cross attention ----
        add_q<<<NROW, 256, 0, stream>>>(tgt, qe, qin);
        launch_m<float, false, false>(stream, qin, 256, off_w + (size_t)i * 65536, 256,
                                      off_b + i * 256, offb, 256, NROW, 256, 256);
        launch_m<float, false, false>(stream, qin, 256, aw_w + (size_t)i * 32768, 256,
                                      aw_b + i * 128, awb, 128, NROW, 128, 256);
        aw_softmax<<<(NROW * 8 + 255) / 256, 256, 0, stream>>>(awb);
        if (nb > 0) {
            for (int bg = 0; bg < 8 / nb; bg++) {
                value2_mgemm<<<dim3((SSP + 127) / 128, 4, nb), 256, 0, stream>>>(
                    src0, src1, src2, src3, bg * nb, val_w + (size_t)i * 65536, val_b + i * 256,
                    valueBig);
                deform_sample2<<<nb * 300, 256, 0, stream>>>(valueBig, offb, awb, refb,
                                                             samp, bg * nb * 300);
            }
        } else {
            for (int s = 0; s < 4; s++) {
                for (int bg = 0; bg < 4; bg++) {
                    value_mgemm<<<dim3((SSP + 63) / 64, 2), 256, 0, stream>>>(
                        src0, src1, src2, src3, bg * 2, val_w + (size_t)i * 65536, val_b + i * 256,
                        valueBig, s * 64);
                    deform_sample<<<600, 64, 0, stream>>>(valueBig, s * 2, offb, awb, refb,
                                                          samp, bg * 600);
                }
            }
        }
        launch_m<float, false, false>(stream, samp, 256, cao_w + (size_t)i * 65536, 256,
                                      cao_b + i * 256, proj, 256, NROW, 256, 256);
        add_ln<<<NROW, 256, 0, stream>>>(tgt, proj, ln1_w + i * 256, ln1_b + i * 256, nullptr);

        // ---- FFN, hidden split 2x512 into ffnh(bigA) ----
        launch_m<double, true, false>(stream, tgt, 256, ff1_w + (size_t)i * 262144, 256,
                                      ff1_b + i * 1024, ffnh, 512, NROW, 512, 256);
        launch_m<float, false, false>(stream, ffnh, 512, ff2_w + (size_t)i * 262144, 1024,
                                      ff2_b + i * 256, proj, 256, NROW, 256, 512);
        launch_m<double, true, false>(stream, tgt, 256, ff1_w + (size_t)i * 262144 + 512 * 256, 256,
                                      ff1_b + i * 1024 + 512, ffnh, 512, NROW, 512, 256);
        launch_m<float, false, true>(stream, ffnh, 512, ff2_w + (size_t)i * 262144 + 512, 1024,
                                     nullptr, proj, 256, NROW, 256, 512);
        add_ln<<<NROW, 256, 0, stream>>>(tgt, proj, ln3_w + i * 256, ln3_b + i * 256,
                                         hs_out + (size_t)i * 614400);

        // ---- bbox refinement: bh1(bufB), bh2(bufC) ----
        launch_m<double, true, false>(stream, tgt, 256, bb_w1 + (size_t)(i + 1) * 65536, 256,
                                      bb_b1 + (i + 1) * 256, bh1, 256, NROW, 256, 256);
        launch_m<float, true, false>(stream, bh1, 256, bb_w2 + (size_t)(i + 1) * 65536, 256,
                                     bb_b2 + (i + 1) * 256, bh2, 256, NROW, 256, 256);
        gemm_smallN<<<(NROW * 4 + 255) / 256, 256, 0, stream>>>(
            bh2, 256, bb_w3 + (size_t)(i + 1) * 1024, bb_b3 + (i + 1) * 4, bb4, 4, NROW);
        ref_update<<<(NROW * 4 + 255) / 256, 256, 0, stream>>>(bb4, refb, refs_out + (size_t)i * 9600);

        // ---- logits ----
        launch_m<double, false, false>(stream, tgt, 256, cls_w + (size_t)(i + 1) * 20736, 256,
                                       cls_b + (i + 1) * 81, log_out + (size_t)i * 194400,
                                       81, NROW, 81, 256);
    }
}

// Round 5
// 6061.602 us; speedup vs baseline: 2.9975x; 1.0464x over previous
//
#include <hip/hip_runtime.h>
#include <cstdint>

#define SSP   13294      // total spatial tokens (100^2+50^2+25^2+13^2)
#define NROW  2400       // B*NQ
#define NROWP 2432

typedef double v4d __attribute__((ext_vector_type(4)));

__device__ __forceinline__ double sigd(double x) { return 1.0 / (1.0 + exp(-x)); }
__device__ __forceinline__ double invsigd(double x) {
    x = fmin(fmax(x, 0.0), 1.0);
    return log(fmax(x, 1e-5) / fmax(1.0 - x, 1e-5));
}
__device__ __forceinline__ double rdA(const float* a, size_t k) { return (double)a[k]; }
__device__ __forceinline__ double rdA(const double* a, size_t k) { return a[k]; }

// Self-calibrating probe for the f64 MFMA C/D row mapping (verified working r2).
__device__ __forceinline__ void mfma_rowmap(int lane, int* rm) {
    v4d c = {0., 0., 0., 0.};
    double a = (double)(lane & 15);
    c = __builtin_amdgcn_mfma_f64_16x16x4f64(a, 0.25, c, 0, 0, 0);
#pragma unroll
    for (int r = 0; r < 4; r++) rm[r] = (int)(c[r] + 0.5);
}

// ---- fp64 MFMA GEMM, BK=32: C (+)= relu?(A(MxK) @ W(NxK)^T + bias) ----------
// 64x64 tile, 4 waves x 32x32 quadrant, 2x2 mfma_f64_16x16x4 frags.
// Per-acc MFMA k-order identical to BK=16 version -> bit-identical results.
template<typename TA, bool RELU, bool ACC>
__global__ __launch_bounds__(256)
void mgemm(const TA* __restrict__ A, int lda,
           const float* __restrict__ W, int ldb,
           const float* __restrict__ bias,
           float* __restrict__ C, int ldc,
           int M, int N, int K)
{
    __shared__ double As[32][67];
    __shared__ double Bs[32][67];
    int bm = blockIdx.x * 64, bn = blockIdx.y * 64;
    int tid = threadIdx.x;
    int lane = tid & 63, wave = tid >> 6;
    int wm = (wave >> 1) * 32, wn = (wave & 1) * 32;
    int j = lane & 15, q = lane >> 4;
    int kk = tid & 31, r0 = tid >> 5;     // staging: 8 rows per 256-thr pass
    int rowmap[4];
    mfma_rowmap(lane, rowmap);
    v4d acc[2][2];
#pragma unroll
    for (int fm = 0; fm < 2; fm++)
#pragma unroll
        for (int fn = 0; fn < 2; fn++)
#pragma unroll
            for (int i = 0; i < 4; i++) acc[fm][fn][i] = 0.0;

    for (int k0 = 0; k0 < K; k0 += 32) {
#pragma unroll
        for (int rr = 0; rr < 8; rr++) {
            int r = r0 + rr * 8;
            int am = bm + r; if (am > M - 1) am = M - 1;
            As[kk][r] = rdA(A, (size_t)am * lda + k0 + kk);
            int wn_ = bn + r; if (wn_ > N - 1) wn_ = N - 1;
            Bs[kk][r] = (double)W[(size_t)wn_ * ldb + k0 + kk];
        }
        __syncthreads();
#pragma unroll
        for (int kst = 0; kst < 8; kst++) {
            int krow = kst * 4 + q;
            double a0 = As[krow][wm + j];
            double a1 = As[krow][wm + 16 + j];
            double b0 = Bs[krow][wn + j];
            double b1 = Bs[krow][wn + 16 + j];
            acc[0][0] = __builtin_amdgcn_mfma_f64_16x16x4f64(a0, b0, acc[0][0], 0, 0, 0);
            acc[0][1] = __builtin_amdgcn_mfma_f64_16x16x4f64(a0, b1, acc[0][1], 0, 0, 0);
            acc[1][0] = __builtin_amdgcn_mfma_f64_16x16x4f64(a1, b0, acc[1][0], 0, 0, 0);
            acc[1][1] = __builtin_amdgcn_mfma_f64_16x16x4f64(a1, b1, acc[1][1], 0, 0, 0);
        }
        __syncthreads();
    }
#pragma unroll
    for (int fm = 0; fm < 2; fm++)
#pragma unroll
        for (int fn = 0; fn < 2; fn++)
#pragma unroll
            for (int i = 0; i < 4; i++) {
                int gm = bm + wm + fm * 16 + rowmap[i];
                int gn = bn + wn + fn * 16 + j;
                if (gm < M && gn < N) {
                    double v = acc[fm][fn][i] + (bias ? (double)bias[gn] : 0.0);
                    if (ACC) v += (double)C[(size_t)gm * ldc + gn];
                    if (RELU) v = fmax(v, 0.0);
                    C[(size_t)gm * ldc + gn] = (float)v;
                }
            }
}

template<typename TA, bool RELU, bool ACC>
static void launch_m(hipStream_t st, const TA* A, int lda, const float* W, int ldb,
                     const float* bias, float* C, int ldc, int M, int N, int K)
{
    dim3 grid((M + 63) / 64, (N + 63) / 64, 1);
    mgemm<TA, RELU, ACC><<<grid, 256, 0, st>>>(A, lda, W, ldb, bias, C, ldc, M, N, K);
}

// -- OLD value GEMM (fallback), 64-ch slice, 2 batches, BK=16 ------------------
__global__ __launch_bounds__(256)
void value_mgemm(const float* __restrict__ s0, const float* __restrict__ s1,
                 const float* __restrict__ s2, const float* __restrict__ s3,
                 int b0, const float* __restrict__ W, const float* __restrict__ bias,
                 float* __restrict__ outv, int c0)
{
    __shared__ double As[16][66];
    __shared__ double Bs[16][66];
    int bm = blockIdx.x * 64;
    int b = b0 + blockIdx.y;
    size_t obase = (size_t)blockIdx.y * SSP * 64;
    int tid = threadIdx.x;
    int lane = tid & 63, wave = tid >> 6;
    int wm = (wave >> 1) * 32, wn = (wave & 1) * 32;
    int j = lane & 15, q = lane >> 4;
    int ka = tid >> 4, ra0 = tid & 15;
    int kb = tid & 15, rb0 = tid >> 4;
    int rowmap[4];
    mfma_rowmap(lane, rowmap);
    v4d acc[2][2];
#pragma unroll
    for (int fm = 0; fm < 2; fm++)
#pragma unroll
        for (int fn = 0; fn < 2; fn++)
#pragma unroll
            for (int i = 0; i < 4; i++) acc[fm][fn][i] = 0.0;

    for (int k0 = 0; k0 < 256; k0 += 16) {
#pragma unroll
        for (int rr = 0; rr < 4; rr++) {
            int ra = ra0 + rr * 16;
            int t = bm + ra; if (t > SSP - 1) t = SSP - 1;
            const float* sb; int hw, s;
            if (t < 10000)      { sb = s0; hw = 10000; s = t; }
            else if (t < 12500) { sb = s1; hw = 2500;  s = t - 10000; }
            else if (t < 13125) { sb = s2; hw = 625;   s = t - 12500; }
            else                { sb = s3; hw = 169;   s = t - 13125; }
            As[ka][ra] = (double)sb[(size_t)(b * 256 + k0 + ka) * hw + s];
            int rb = rb0 + rr * 16;
            Bs[kb][rb] = (double)W[(size_t)(c0 + rb) * 256 + k0 + kb];
        }
        __syncthreads();
#pragma unroll
        for (int kst = 0; kst < 4; kst++) {
            int krow = kst * 4 + q;
            double a0 = As[krow][wm + j];
            double a1 = As[krow][wm + 16 + j];
            double b0v = Bs[krow][wn + j];
            double b1v = Bs[krow][wn + 16 + j];
            acc[0][0] = __builtin_amdgcn_mfma_f64_16x16x4f64(a0, b0v, acc[0][0], 0, 0, 0);
            acc[0][1] = __builtin_amdgcn_mfma_f64_16x16x4f64(a0, b1v, acc[0][1], 0, 0, 0);
            acc[1][0] = __builtin_amdgcn_mfma_f64_16x16x4f64(a1, b0v, acc[1][0], 0, 0, 0);
            acc[1][1] = __builtin_amdgcn_mfma_f64_16x16x4f64(a1, b1v, acc[1][1], 0, 0, 0);
        }
        __syncthreads();
    }
#pragma unroll
    for (int fm = 0; fm < 2; fm++)
#pragma unroll
        for (int fn = 0; fn < 2; fn++)
#pragma unroll
            for (int i = 0; i < 4; i++) {
                int gm = bm + wm + fm * 16 + rowmap[i];
                int gn = wn + fn * 16 + j;
                if (gm < SSP)
                    outv[obase + (size_t)gm * 64 + gn] = (float)(acc[fm][fn][i] + (double)bias[c0 + gn]);
            }
}

// -- value GEMM, BK=32: full 256 ch, nb batches; BM=128/BN=64, grid(104,4,nb) --
// Per-acc MFMA k-order identical to BK=16 -> bit-identical.
__global__ __launch_bounds__(256)
void value2_mgemm(const float* __restrict__ s0, const float* __restrict__ s1,
                  const float* __restrict__ s2, const float* __restrict__ s3,
                  int b0, const float* __restrict__ W, const float* __restrict__ bias,
                  float* __restrict__ outv)
{
    __shared__ double As[32][130];
    __shared__ double Bs[32][67];
    int bm = blockIdx.x * 128;
    int bn = blockIdx.y * 64;
    int b = b0 + blockIdx.z;
    size_t obase = (size_t)blockIdx.z * SSP * 256;
    int tid = threadIdx.x;
    int lane = tid & 63, wave = tid >> 6;
    int wm = (wave >> 1) * 64, wn = (wave & 1) * 32;
    int j = lane & 15, q = lane >> 4;
    int rowmap[4];
    mfma_rowmap(lane, rowmap);
    // A staging: thread owns one token column (ra), 2 k-rows per pass
    int ra = tid & 127, ka0 = tid >> 7;
    {
        int t = bm + ra; if (t > SSP - 1) t = SSP - 1;
    }
    const float* sbA; int hwA, sA;
    {
        int t = bm + ra; if (t > SSP - 1) t = SSP - 1;
        if (t < 10000)      { sbA = s0; hwA = 10000; sA = t; }
        else if (t < 12500) { sbA = s1; hwA = 2500;  sA = t - 10000; }
        else if (t < 13125) { sbA = s2; hwA = 625;   sA = t - 12500; }
        else                { sbA = s3; hwA = 169;   sA = t - 13125; }
    }
    int kb = tid & 31, rb0 = tid >> 5;
    v4d acc[4][2];
#pragma unroll
    for (int fm = 0; fm < 4; fm++)
#pragma unroll
        for (int fn = 0; fn < 2; fn++)
#pragma unroll
            for (int i = 0; i < 4; i++) acc[fm][fn][i] = 0.0;

    for (int k0 = 0; k0 < 256; k0 += 32) {
#pragma unroll
        for (int pp = 0; pp < 16; pp++) {
            int kaa = ka0 + pp * 2;
            As[kaa][ra] = (double)sbA[(size_t)(b * 256 + k0 + kaa) * hwA + sA];
        }
#pragma unroll
        for (int pp = 0; pp < 8; pp++) {
            int rb = rb0 + pp * 8;
            Bs[kb][rb] = (double)W[(size_t)(bn + rb) * 256 + k0 + kb];
        }
        __syncthreads();
#pragma unroll
        for (int kst = 0; kst < 8; kst++) {
            int krow = kst * 4 + q;
            double a0 = As[krow][wm + j];
            double a1 = As[krow][wm + 16 + j];
            double a2 = As[krow][wm + 32 + j];
            double a3 = As[krow][wm + 48 + j];
            double b0v = Bs[krow][wn + j];
            double b1v = Bs[krow][wn + 16 + j];
            acc[0][0] = __builtin_amdgcn_mfma_f64_16x16x4f64(a0, b0v, acc[0][0], 0, 0, 0);
            acc[0][1] = __builtin_amdgcn_mfma_f64_16x16x4f64(a0, b1v, acc[0][1], 0, 0, 0);
            acc[1][0] = __builtin_amdgcn_mfma_f64_16x16x4f64(a1, b0v, acc[1][0], 0, 0, 0);
            acc[1][1] = __builtin_amdgcn_mfma_f64_16x16x4f64(a1, b1v, acc[1][1], 0, 0, 0);
            acc[2][0] = __builtin_amdgcn_mfma_f64_16x16x4f64(a2, b0v, acc[2][0], 0, 0, 0);
            acc[2][1] = __builtin_amdgcn_mfma_f64_16x16x4f64(a2, b1v, acc[2][1], 0, 0, 0);
            acc[3][0] = __builtin_amdgcn_mfma_f64_16x16x4f64(a3, b0v, acc[3][0], 0, 0, 0);
            acc[3][1] = __builtin_amdgcn_mfma_f64_16x16x4f64(a3, b1v, acc[3][1], 0, 0, 0);
        }
        __syncthreads();
    }
#pragma unroll
    for (int fm = 0; fm < 4; fm++)
#pragma unroll
        for (int fn = 0; fn < 2; fn++)
#pragma unroll
            for (int i = 0; i < 4; i++) {
                int gm = bm + wm + fm * 16 + rowmap[i];
                int gn = bn + wn + fn * 16 + j;
                if (gm < SSP)
                    outv[obase + (size_t)gm * 256 + gn] = (float)(acc[fm][fn][i] + (double)bias[gn]);
            }
}

// ---------------- MHA: 12 q-rows x 1 head per block, K in LDS -----------------
// grid (200, 8), 384 thr. Scores bit-identical (same d-order); softmax-denom /
// PV reduction tree order differs from old kernel (harmless: network continuous).
__global__ __launch_bounds__(384)
void mha12(const float* __restrict__ qk, const float* __restrict__ vbuf,
           float* __restrict__ mha)
{
    int bx = blockIdx.x;                  // 25 blocks per batch
    int b = bx / 25;
    int row0 = b * 300 + (bx % 25) * 12;
    int h = blockIdx.y;
    const double scale = 0.17677669529663687;
    __shared__ float Ks[300][33];
    __shared__ float Qs[12][33];
    __shared__ double sc[12][304];
    int tid = threadIdx.x;
    int r = tid >> 5, lane = tid & 31;
    for (int e = tid; e < 9600; e += 384) {
        int jj = e >> 5, d = e & 31;
        Ks[jj][d] = qk[(size_t)(b * 300 + jj) * 512 + 256 + h * 32 + d];
    }
    Qs[r][lane] = qk[(size_t)(row0 + r) * 512 + h * 32 + lane];
    __syncthreads();
    // QK^T: group r computes row r's 300 scores, serial d (bit-same vs old)
    double mx = -1e300;
    for (int it = 0; it < 10; it++) {
        int jj = lane + it * 32;
        if (jj < 300) {
            double t = 0.;
#pragma unroll
            for (int d = 0; d < 32; d++) t += (double)Qs[r][d] * (double)Ks[jj][d];
            sc[r][jj] = t;
            mx = fmax(mx, t);
        }
    }
#pragma unroll
    for (int o = 16; o > 0; o >>= 1) mx = fmax(mx, __shfl_xor(mx, o));
    double psum = 0.;
    for (int it = 0; it < 10; it++) {
        int jj = lane + it * 32;
        if (jj < 300) {
            double e = exp((sc[r][jj] - mx) * scale);
            sc[r][jj] = e;
            psum += e;
        }
    }
#pragma unroll
    for (int o = 16; o > 0; o >>= 1) psum += __shfl_xor(psum, o);
    double inv = 1.0 / psum;
    __syncthreads();
    // PV: thread (r, d); V from L2, coalesced; 4 independent chains
    const float* vp = vbuf + (size_t)(b * 300) * 256 + h * 32 + lane;
    double o0 = 0., o1 = 0., o2 = 0., o3 = 0.;
    for (int t = 0; t < 300; t += 4) {
        o0 += sc[r][t]     * (double)vp[(size_t)t * 256];
        o1 += sc[r][t + 1] * (double)vp[(size_t)(t + 1) * 256];
        o2 += sc[r][t + 2] * (double)vp[(size_t)(t + 2) * 256];
        o3 += sc[r][t + 3] * (double)vp[(size_t)(t + 3) * 256];
    }
    double o = ((o0 + o1) + (o2 + o3)) * inv;
    mha[(size_t)(row0 + r) * 256 + h * 32 + lane] = (float)o;
}

// ---------------- small-N GEMMs, fp64 math ------------------------------------
__global__ __launch_bounds__(256)
void gemm_small_qe(const float* __restrict__ qe, const float* __restrict__ W,
                   const float* __restrict__ bias, float* __restrict__ out, int N, int M)
{
    int t = blockIdx.x * 256 + threadIdx.x;
    if (t >= M * N) return;
    int row = t / N, n = t % N;
    const float* a = qe + (size_t)(row % 300) * 512;
    const float* w = W + (size_t)n * 256;
    double s = 0.0;
    for (int k = 0; k < 256; k++) s += (double)a[k] * (double)w[k];
    out[t] = (float)(s + (double)bias[n]);
}
__global__ __launch_bounds__(256)
void gemm_smallN(const float* __restrict__ A, int lda, const float* __restrict__ W,
                 const float* __restrict__ bias, float* __restrict__ out, int N, int M)
{
    int t = blockIdx.x * 256 + threadIdx.x;
    if (t >= M * N) return;
    int row = t / N, n = t % N;
    const float* a = A + (size_t)row * lda;
    const float* w = W + (size_t)n * 256;
    double s = 0.0;
    for (int k = 0; k < 256; k++) s += (double)a[k] * (double)w[k];
    out[t] = (float)(s + (double)bias[n]);
}

// ---------------- tgt init (fp64 residual stream) -----------------------------
__global__ __launch_bounds__(256)
void init_tgt(const float* __restrict__ qe, double* __restrict__ tgt)
{
    int row = blockIdx.x, c = threadIdx.x;
    size_t i = (size_t)row * 256 + c;
    tgt[i] = (row < NROW) ? (double)qe[(size_t)(row % 300) * 512 + 256 + c] : 0.0;
}

__global__ void add_q(const double* __restrict__ tgt, const float* __restrict__ qe,
                      float* __restrict__ qin)
{
    int row = blockIdx.x, c = threadIdx.x;
    size_t i = (size_t)row * 256 + c;
    qin[i] = (float)(tgt[i] + (double)qe[(size_t)(row % 300) * 512 + c]);
}

// ---------------- fused residual-add + LayerNorm, fp64 math -------------------
__global__ __launch_bounds__(256)
void add_ln(double* __restrict__ tgt, const float* __restrict__ br,
            const float* __restrict__ w, const float* __restrict__ b,
            float* __restrict__ hs_out)
{
    int row = blockIdx.x, c = threadIdx.x;
    size_t idx = (size_t)row * 256 + c;
    double v = tgt[idx] + (double)br[idx];
    double s = v, s2 = v * v;
#pragma unroll
    for (int o = 32; o > 0; o >>= 1) { s += __shfl_xor(s, o); s2 += __shfl_xor(s2, o); }
    __shared__ double rs[4], rs2[4];
    int wv = c >> 6;
    if ((c & 63) == 0) { rs[wv] = s; rs2[wv] = s2; }
    __syncthreads();
    double S = rs[0] + rs[1] + rs[2] + rs[3];
    double S2 = rs2[0] + rs2[1] + rs2[2] + rs2[3];
    double mean = S * (1.0 / 256.0);
    double var = S2 * (1.0 / 256.0) - mean * mean;
    double o = (v - mean) / sqrt(var + 1e-5) * (double)w[c] + (double)b[c];
    tgt[idx] = o;
    if (hs_out) hs_out[idx] = (float)o;
}

// ---------------- attention-weight softmax over 16 per (row,h), fp64 ----------
__global__ __launch_bounds__(256)
void aw_softmax(float* __restrict__ buf)
{
    int t = blockIdx.x * 256 + threadIdx.x;
    if (t >= NROW * 8) return;
    int row = t >> 3, h = t & 7;
    float* p = buf + (size_t)row * 128 + h * 16;
    double mx = -1e300, e[16];
#pragma unroll
    for (int j = 0; j < 16; j++) mx = fmax(mx, (double)p[j]);
    double s = 0.;
#pragma unroll
    for (int j = 0; j < 16; j++) { e[j] = exp((double)p[j] - mx); s += e[j]; }
    double inv = 1.0 / s;
#pragma unroll
    for (int j = 0; j < 16; j++) p[j] = (float)(e[j] * inv);
}

// ------ OLD sampler (fallback): value 2 batches x 64 ch slice -----------------
__global__ __launch_bounds__(64)
void deform_sample(const float* __restrict__ value, int h0,
                   const float* __restrict__ offb, const float* __restrict__ awsm,
                   const double* __restrict__ ref, float* __restrict__ out, int row0)
{
    int row = row0 + blockIdx.x;
    int hl = threadIdx.x >> 5, d = threadIdx.x & 31;
    int h = h0 + hl;
    double rx = ref[row * 4 + 0], ry = ref[row * 4 + 1];
    double rw = ref[row * 4 + 2], rh = ref[row * 4 + 3];
    const float* offr = offb + (size_t)row * 256;
    const float* awr = awsm + (size_t)row * 128 + h * 16;
    size_t vbase = (size_t)(blockIdx.x / 300) * SSP * 64 + hl * 32 + d;
    const int LH[4] = {100, 50, 25, 13};
    const int LW[4] = {100, 50, 25, 13};
    const int LS[4] = {0, 10000, 12500, 13125};
    double acc = 0.;
#pragma unroll
    for (int l = 0; l < 4; l++) {
        int Hh = LH[l], Ww = LW[l], st = LS[l];
#pragma unroll
        for (int p = 0; p < 4; p++) {
            double ox = (double)offr[(h * 32) + l * 8 + p * 2 + 0];
            double oy = (double)offr[(h * 32) + l * 8 + p * 2 + 1];
            double aw = (double)awr[l * 4 + p];
            double x = (rx + ox * 0.125 * rw) * Ww - 0.5;
            double y = (ry + oy * 0.125 * rh) * Hh - 0.5;
            double xf = floor(x), yf = floor(y);
            double dx = x - xf, dy = y - yf;
            int x0 = (int)xf, y0 = (int)yf;
            double w00 = (1 - dx) * (1 - dy), w10 = dx * (1 - dy);
            double w01 = (1 - dx) * dy, w11 = dx * dy;
#define CORN(X, Y, W)                                                              \
            if ((unsigned)(X) < (unsigned)Ww && (unsigned)(Y) < (unsigned)Hh)      \
                acc += (W) * aw * (double)value[vbase + (size_t)(st + (Y) * Ww + (X)) * 64];
            CORN(x0, y0, w00) CORN(x0 + 1, y0, w10) CORN(x0, y0 + 1, w01) CORN(x0 + 1, y0 + 1, w11)
#undef CORN
        }
    }
    out[(size_t)row * 256 + h * 32 + d] = (float)acc;
}

// ------ NEW sampler: value [bslot][token][256], all 8 heads per block ---------
__global__ __launch_bounds__(256)
void deform_sample2(const float* __restrict__ value,
                    const float* __restrict__ offb, const float* __restrict__ awsm,
                    const double* __restrict__ ref, float* __restrict__ out, int row0)
{
    int row = row0 + blockIdx.x;
    int h = threadIdx.x >> 5, d = threadIdx.x & 31;
    double rx = ref[row * 4 + 0], ry = ref[row * 4 + 1];
    double rw = ref[row * 4 + 2], rh = ref[row * 4 + 3];
    const float* offr = offb + (size_t)row * 256;
    const float* awr = awsm + (size_t)row * 128 + h * 16;
    size_t vbase = (size_t)(blockIdx.x / 300) * SSP * 256 + h * 32 + d;
    const int LH[4] = {100, 50, 25, 13};
    const int LW[4] = {100, 50, 25, 13};
    const int LS[4] = {0, 10000, 12500, 13125};
    double acc = 0.;
#pragma unroll
    for (int l = 0; l < 4; l++) {
        int Hh = LH[l], Ww = LW[l], st = LS[l];
#pragma unroll
        for (int p = 0; p < 4; p++) {
            double ox = (double)offr[(h * 32) + l * 8 + p * 2 + 0];
            double oy = (double)offr[(h * 32) + l * 8 + p * 2 + 1];
            double aw = (double)awr[l * 4 + p];
            double x = (rx + ox * 0.125 * rw) * Ww - 0.5;
            double y = (ry + oy * 0.125 * rh) * Hh - 0.5;
            double xf = floor(x), yf = floor(y);
            double dx = x - xf, dy = y - yf;
            int x0 = (int)xf, y0 = (int)yf;
            double w00 = (1 - dx) * (1 - dy), w10 = dx * (1 - dy);
            double w01 = (1 - dx) * dy, w11 = dx * dy;
#define CORN(X, Y, W)                                                              \
            if ((unsigned)(X) < (unsigned)Ww && (unsigned)(Y) < (unsigned)Hh)      \
                acc += (W) * aw * (double)value[vbase + (size_t)(st + (Y) * Ww + (X)) * 256];
            CORN(x0, y0, w00) CORN(x0 + 1, y0, w10) CORN(x0, y0 + 1, w01) CORN(x0 + 1, y0 + 1, w11)
#undef CORN
        }
    }
    out[(size_t)row * 256 + h * 32 + d] = (float)acc;
}

// ---------------- ref init / update (fp64 state, fp32 refs out) ---------------
__global__ void ref_init(const float* __restrict__ lin2, const float* __restrict__ bb,
                         double* __restrict__ ref)
{
    int t = blockIdx.x * 256 + threadIdx.x;
    if (t >= NROW) return;
#pragma unroll
    for (int j = 0; j < 2; j++) {
        double r2 = sigd((double)lin2[t * 2 + j]);
        ref[t * 4 + j] = sigd((double)bb[t * 4 + j] + invsigd(r2));
    }
    ref[t * 4 + 2] = sigd((double)bb[t * 4 + 2]);
    ref[t * 4 + 3] = sigd((double)bb[t * 4 + 3]);
}
__global__ void ref_update(const float* __restrict__ bb, double* __restrict__ ref,
                           float* __restrict__ refs_out)
{
    int t = blockIdx.x * 256 + threadIdx.x;
    if (t >= NROW * 4) return;
    double nv = sigd((double)bb[t] + invsigd(ref[t]));
    ref[t] = nv;
    refs_out[t] = (float)nv;
}

// =============================== launcher =====================================
extern "C" void kernel_launch(void* const* d_in, const int* in_sizes, int n_in,
                              void* d_out, int out_size, void* d_ws, size_t ws_size,
                              hipStream_t stream)
{
    const float* src0 = (const float*)d_in[0];
    const float* src1 = (const float*)d_in[2];
    const float* src2 = (const float*)d_in[4];
    const float* src3 = (const float*)d_in[6];
    const float* qe = (const float*)d_in[8];
    const float* ref_w = (const float*)d_in[9];
    const float* ref_b = (const float*)d_in[10];
    const float* sa_in_w = (const float*)d_in[11];
    const float* sa_in_b = (const float*)d_in[12];
    const float* sa_out_w = (const float*)d_in[13];
    const float* sa_out_b = (const float*)d_in[14];
    const float* off_w = (const float*)d_in[15];
    const float* off_b = (const float*)d_in[16];
    const float* aw_w = (const float*)d_in[17];
    const float* aw_b = (const float*)d_in[18];
    const float* val_w = (const float*)d_in[19];
    const float* val_b = (const float*)d_in[20];
    const float* cao_w = (const float*)d_in[21];
    const float* cao_b = (const float*)d_in[22];
    const float* ln1_w = (const float*)d_in[23];
    const float* ln1_b = (const float*)d_in[24];
    const float* ln2_w = (const float*)d_in[25];
    const float* ln2_b = (const float*)d_in[26];
    const float* ln3_w = (const float*)d_in[27];
    const float* ln3_b = (const float*)d_in[28];
    const float* ff1_w = (const float*)d_in[29];
    const float* ff1_b = (const float*)d_in[30];
    const float* ff2_w = (const float*)d_in[31];
    const float* ff2_b = (const float*)d_in[32];
    const float* bb_w1 = (const float*)d_in[33];
    const float* bb_b1 = (const float*)d_in[34];
    const float* bb_w2 = (const float*)d_in[35];
    const float* bb_b2 = (const float*)d_in[36];
    const float* bb_w3 = (const float*)d_in[37];
    const float* bb_b3 = (const float*)d_in[38];
    const float* cls_w = (const float*)d_in[39];
    const float* cls_b = (const float*)d_in[40];

    char* wsp = (char*)d_ws;
    size_t off_ws = 0;
    auto alloc = [&](size_t bytes) -> char* {
        char* p = wsp + off_ws;
        off_ws += (bytes + 255) & ~(size_t)255;
        return p;
    };
    // unified layout: fixed buffers first, then proj/bufC, then open-ended value
    // region starting at proj (proj and bufC are dead during the deform loop).
    double* tgt  = (double*)alloc((size_t)NROWP * 256 * 8);  // 4.98 MB fp64 residual
    char* bigA = alloc((size_t)NROWP * 512 * 4);             // 4.98 union
    float* qk   = (float*)bigA;
    float* ffnh = (float*)bigA;
    float* offb = (float*)bigA;
    float* awb  = (float*)(bigA + (size_t)NROWP * 256 * 4);
    char* bufB = alloc((size_t)NROWP * 256 * 4);             // 2.49 union
    float* vbuf = (float*)bufB;
    float* samp = (float*)bufB;
    float* bh1  = (float*)bufB;
    float* bb4   = (float*)alloc((size_t)NROWP * 4 * 4);
    double* refb = (double*)alloc((size_t)NROWP * 4 * 8);
    float* rlin2 = (float*)alloc((size_t)NROWP * 2 * 4);
    size_t val_off = off_ws;
    float* proj = (float*)alloc((size_t)NROWP * 256 * 4);    // 2.49
    char* bufC  = alloc((size_t)NROWP * 256 * 4);            // 2.49 union
    float* qin = (float*)bufC;
    float* mhab = (float*)bufC;
    float* bh2 = (float*)bufC;
    float* valueBig = proj;   // value region spans proj, bufC, and ws tail

    // path selection by available workspace beyond val_off
    size_t avail = ws_size > val_off ? ws_size - val_off : 0;
    int nb = 0;               // batches of full-256ch value held at once
    if (avail >= (size_t)2 * SSP * 256 * 4 + 4096) nb = 2;
    else if (avail >= (size_t)SSP * 256 * 4 + 4096) nb = 1;
    // nb==0 -> fallback 64-ch-slice path (needs 6.81 MB at val_off, proven safe)

    float* out_f = (float*)d_out;
    float* hs_out = out_f;                                   // 6 * 614400
    float* refs_out = out_f + (size_t)6 * 614400;            // 6 * 9600
    float* log_out = refs_out + (size_t)6 * 9600;            // 6 * 194400

    // ---- setup ----
    init_tgt<<<NROWP, 256, 0, stream>>>(qe, tgt);
    gemm_small_qe<<<(NROW * 2 + 255) / 256, 256, 0, stream>>>(qe, ref_w, ref_b, rlin2, 2, NROW);
    launch_m<double, true, false>(stream, tgt, 256, bb_w1, 256, bb_b1, bh1, 256, NROW, 256, 256);
    launch_m<float, true, false>(stream, bh1, 256, bb_w2, 256, bb_b2, proj, 256, NROW, 256, 256);
    gemm_smallN<<<(NROW * 4 + 255) / 256, 256, 0, stream>>>(proj, 256, bb_w3, bb_b3, bb4, 4, NROW);
    ref_init<<<(NROW + 255) / 256, 256, 0, stream>>>(rlin2, bb4, refb);

    for (int i = 0; i < 6; i++) {
        // ---- self attention ----
        add_q<<<NROW, 256, 0, stream>>>(tgt, qe, qin);
        launch_m<float, false, false>(stream, qin, 256, sa_in_w + (size_t)i * 196608, 256,
                                      sa_in_b + i * 768, qk, 512, NROW, 512, 256);
        launch_m<double, false, false>(stream, tgt, 256, sa_in_w + (size_t)i * 196608 + 131072, 256,
                                       sa_in_b + i * 768 + 512, vbuf, 256, NROW, 256, 256);
        mha12<<<dim3(200, 8), 384, 0, stream>>>(qk, vbuf, mhab);
        launch_m<float, false, false>(stream, mhab, 256, sa_out_w + (size_t)i * 65536, 256,
                                      sa_out_b + i * 256, proj, 256, NROW, 256, 256);
        add_ln<<<NROW, 256, 0, stream>>>(tgt, proj, ln2_w + i * 256, ln2_b + i * 256, nullptr);

        // ---- deformable cross attention ----
        add_q<<<NROW, 256, 0, stream>>>(tgt, qe, qin);
        launch_m<float, false, false>(stream, qin, 256, off_w + (size_t)i * 65536, 256,
                                      off_b + i * 256, offb, 256, NROW, 256, 256);
        launch_m<float, false, false>(stream, qin, 256, aw_w + (size_t)i * 32768, 256,
                                      aw_b + i * 128, awb, 128, NROW, 128, 256);
        aw_softmax<<<(NROW * 8 + 255) / 256, 256, 0, stream>>>(awb);
        if (nb > 0) {
            for (int bg = 0; bg < 8 / nb; bg++) {
                value2_mgemm<<<dim3((SSP + 127) / 128, 4, nb), 256, 0, stream>>>(
                    src0, src1, src2, src3, bg * nb, val_w + (size_t)i * 65536, val_b + i * 256,
                    valueBig);
                deform_sample2<<<nb * 300, 256, 0, stream>>>(valueBig, offb, awb, refb,
                                                             samp, bg * nb * 300);
            }
        } else {
            for (int s = 0; s < 4; s++) {
                for (int bg = 0; bg < 4; bg++) {
                    value_mgemm<<<dim3((SSP + 63) / 64, 2), 256, 0, stream>>>(
                        src0, src1, src2, src3, bg * 2, val_w + (size_t)i * 65536, val_b + i * 256,
                        valueBig, s * 64);
                    deform_sample<<<600, 64, 0, stream>>>(valueBig, s * 2, offb, awb, refb,
                                                          samp, bg * 600);
                }
            }
        }
        launch_m<float, false, false>(stream, samp, 256, cao_w + (size_t)i * 65536, 256,
                                      cao_b + i * 256, proj, 256, NROW, 256, 256);
        add_ln<<<NROW, 256, 0, stream>>>(tgt, proj, ln1_w + i * 256, ln1_b + i * 256, nullptr);

        // ---- FFN, hidden split 2x512 into ffnh(bigA) ----
        launch_m<double, true, false>(stream, tgt, 256, ff1_w + (size_t)i * 262144, 256,
                                      ff1_b + i * 1024, ffnh, 512, NROW, 512, 256);
        launch_m<float, false, false>(stream, ffnh, 512, ff2_w + (size_t)i * 262144, 1024,
                                      ff2_b + i * 256, proj, 256, NROW, 256, 512);
        launch_m<double, true, false>(stream, tgt, 256, ff1_w + (size_t)i * 262144 + 512 * 256, 256,
                                      ff1_b + i * 1024 + 512, ffnh, 512, NROW, 512, 256);
        launch_m<float, false, true>(stream, ffnh, 512, ff2_w + (size_t)i * 262144 + 512, 1024,
                                     nullptr, proj, 256, NROW, 256, 512);
        add_ln<<<NROW, 256, 0, stream>>>(tgt, proj, ln3_w + i * 256, ln3_b + i * 256,
                                         hs_out + (size_t)i * 614400);

        // ---- bbox refinement: bh1(bufB), bh2(bufC) ----
        launch_m<double, true, false>(stream, tgt, 256, bb_w1 + (size_t)(i + 1) * 65536, 256,
                                      bb_b1 + (i + 1) * 256, bh1, 256, NROW, 256, 256);
        launch_m<float, true, false>(stream, bh1, 256, bb_w2 + (size_t)(i + 1) * 65536, 256,
                                     bb_b2 + (i + 1) * 256, bh2, 256, NROW, 256, 256);
        gemm_smallN<<<(NROW * 4 + 255) / 256, 256, 0, stream>>>(
            bh2, 256, bb_w3 + (size_t)(i + 1) * 1024, bb_b3 + (i + 1) * 4, bb4, 4, NROW);
        ref_update<<<(NROW * 4 + 255) / 256, 256, 0, stream>>>(bb4, refb, refs_out + (size_t)i * 9600);

        // ---- logits ----
        launch_m<double, false, false>(stream, tgt, 256, cls_w + (size_t)(i + 1) * 20736, 256,
                                       cls_b + (i + 1) * 81, log_out + (size_t)i * 194400,
                                       81, NROW, 81, 256);
    }
}

// Round 6
// 5612.895 us; speedup vs baseline: 3.2371x; 1.0799x over previous
//
#include <hip/hip_runtime.h>
#include <cstdint>

#define SSP   13294      // total spatial tokens (100^2+50^2+25^2+13^2)
#define NROW  2400       // B*NQ
#define NROWP 2432

typedef double v4d __attribute__((ext_vector_type(4)));

__device__ __forceinline__ double sigd(double x) { return 1.0 / (1.0 + exp(-x)); }
__device__ __forceinline__ double invsigd(double x) {
    x = fmin(fmax(x, 0.0), 1.0);
    return log(fmax(x, 1e-5) / fmax(1.0 - x, 1e-5));
}
__device__ __forceinline__ double rdA(const float* a, size_t k) { return (double)a[k]; }
__device__ __forceinline__ double rdA(const double* a, size_t k) { return a[k]; }

// Self-calibrating probe for the f64 MFMA C/D row mapping (verified working r2).
__device__ __forceinline__ void mfma_rowmap(int lane, int* rm) {
    v4d c = {0., 0., 0., 0.};
    double a = (double)(lane & 15);
    c = __builtin_amdgcn_mfma_f64_16x16x4f64(a, 0.25, c, 0, 0, 0);
#pragma unroll
    for (int r = 0; r < 4; r++) rm[r] = (int)(c[r] + 0.5);
}

// ---- fp64 MFMA GEMM, BK=32: C (+)= relu?(A(MxK) @ W(NxK)^T + bias) ----------
template<typename TA, bool RELU, bool ACC>
__global__ __launch_bounds__(256)
void mgemm(const TA* __restrict__ A, int lda,
           const float* __restrict__ W, int ldb,
           const float* __restrict__ bias,
           float* __restrict__ C, int ldc,
           int M, int N, int K)
{
    __shared__ double As[32][67];
    __shared__ double Bs[32][67];
    int bm = blockIdx.x * 64, bn = blockIdx.y * 64;
    int tid = threadIdx.x;
    int lane = tid & 63, wave = tid >> 6;
    int wm = (wave >> 1) * 32, wn = (wave & 1) * 32;
    int j = lane & 15, q = lane >> 4;
    int kk = tid & 31, r0 = tid >> 5;
    int rowmap[4];
    mfma_rowmap(lane, rowmap);
    v4d acc[2][2];
#pragma unroll
    for (int fm = 0; fm < 2; fm++)
#pragma unroll
        for (int fn = 0; fn < 2; fn++)
#pragma unroll
            for (int i = 0; i < 4; i++) acc[fm][fn][i] = 0.0;

    for (int k0 = 0; k0 < K; k0 += 32) {
#pragma unroll
        for (int rr = 0; rr < 8; rr++) {
            int r = r0 + rr * 8;
            int am = bm + r; if (am > M - 1) am = M - 1;
            As[kk][r] = rdA(A, (size_t)am * lda + k0 + kk);
            int wn_ = bn + r; if (wn_ > N - 1) wn_ = N - 1;
            Bs[kk][r] = (double)W[(size_t)wn_ * ldb + k0 + kk];
        }
        __syncthreads();
#pragma unroll
        for (int kst = 0; kst < 8; kst++) {
            int krow = kst * 4 + q;
            double a0 = As[krow][wm + j];
            double a1 = As[krow][wm + 16 + j];
            double b0 = Bs[krow][wn + j];
            double b1 = Bs[krow][wn + 16 + j];
            acc[0][0] = __builtin_amdgcn_mfma_f64_16x16x4f64(a0, b0, acc[0][0], 0, 0, 0);
            acc[0][1] = __builtin_amdgcn_mfma_f64_16x16x4f64(a0, b1, acc[0][1], 0, 0, 0);
            acc[1][0] = __builtin_amdgcn_mfma_f64_16x16x4f64(a1, b0, acc[1][0], 0, 0, 0);
            acc[1][1] = __builtin_amdgcn_mfma_f64_16x16x4f64(a1, b1, acc[1][1], 0, 0, 0);
        }
        __syncthreads();
    }
#pragma unroll
    for (int fm = 0; fm < 2; fm++)
#pragma unroll
        for (int fn = 0; fn < 2; fn++)
#pragma unroll
            for (int i = 0; i < 4; i++) {
                int gm = bm + wm + fm * 16 + rowmap[i];
                int gn = bn + wn + fn * 16 + j;
                if (gm < M && gn < N) {
                    double v = acc[fm][fn][i] + (bias ? (double)bias[gn] : 0.0);
                    if (ACC) v += (double)C[(size_t)gm * ldc + gn];
                    if (RELU) v = fmax(v, 0.0);
                    C[(size_t)gm * ldc + gn] = (float)v;
                }
            }
}

template<typename TA, bool RELU, bool ACC>
static void launch_m(hipStream_t st, const TA* A, int lda, const float* W, int ldb,
                     const float* bias, float* C, int ldc, int M, int N, int K)
{
    dim3 grid((M + 63) / 64, (N + 63) / 64, 1);
    mgemm<TA, RELU, ACC><<<grid, 256, 0, st>>>(A, lda, W, ldb, bias, C, ldc, M, N, K);
}

// -- OLD value GEMM (fallback), 64-ch slice, 2 batches, BK=16 ------------------
__global__ __launch_bounds__(256)
void value_mgemm(const float* __restrict__ s0, const float* __restrict__ s1,
                 const float* __restrict__ s2, const float* __restrict__ s3,
                 int b0, const float* __restrict__ W, const float* __restrict__ bias,
                 float* __restrict__ outv, int c0)
{
    __shared__ double As[16][66];
    __shared__ double Bs[16][66];
    int bm = blockIdx.x * 64;
    int b = b0 + blockIdx.y;
    size_t obase = (size_t)blockIdx.y * SSP * 64;
    int tid = threadIdx.x;
    int lane = tid & 63, wave = tid >> 6;
    int wm = (wave >> 1) * 32, wn = (wave & 1) * 32;
    int j = lane & 15, q = lane >> 4;
    int ka = tid >> 4, ra0 = tid & 15;
    int kb = tid & 15, rb0 = tid >> 4;
    int rowmap[4];
    mfma_rowmap(lane, rowmap);
    v4d acc[2][2];
#pragma unroll
    for (int fm = 0; fm < 2; fm++)
#pragma unroll
        for (int fn = 0; fn < 2; fn++)
#pragma unroll
            for (int i = 0; i < 4; i++) acc[fm][fn][i] = 0.0;

    for (int k0 = 0; k0 < 256; k0 += 16) {
#pragma unroll
        for (int rr = 0; rr < 4; rr++) {
            int ra = ra0 + rr * 16;
            int t = bm + ra; if (t > SSP - 1) t = SSP - 1;
            const float* sb; int hw, s;
            if (t < 10000)      { sb = s0; hw = 10000; s = t; }
            else if (t < 12500) { sb = s1; hw = 2500;  s = t - 10000; }
            else if (t < 13125) { sb = s2; hw = 625;   s = t - 12500; }
            else                { sb = s3; hw = 169;   s = t - 13125; }
            As[ka][ra] = (double)sb[(size_t)(b * 256 + k0 + ka) * hw + s];
            int rb = rb0 + rr * 16;
            Bs[kb][rb] = (double)W[(size_t)(c0 + rb) * 256 + k0 + kb];
        }
        __syncthreads();
#pragma unroll
        for (int kst = 0; kst < 4; kst++) {
            int krow = kst * 4 + q;
            double a0 = As[krow][wm + j];
            double a1 = As[krow][wm + 16 + j];
            double b0v = Bs[krow][wn + j];
            double b1v = Bs[krow][wn + 16 + j];
            acc[0][0] = __builtin_amdgcn_mfma_f64_16x16x4f64(a0, b0v, acc[0][0], 0, 0, 0);
            acc[0][1] = __builtin_amdgcn_mfma_f64_16x16x4f64(a0, b1v, acc[0][1], 0, 0, 0);
            acc[1][0] = __builtin_amdgcn_mfma_f64_16x16x4f64(a1, b0v, acc[1][0], 0, 0, 0);
            acc[1][1] = __builtin_amdgcn_mfma_f64_16x16x4f64(a1, b1v, acc[1][1], 0, 0, 0);
        }
        __syncthreads();
    }
#pragma unroll
    for (int fm = 0; fm < 2; fm++)
#pragma unroll
        for (int fn = 0; fn < 2; fn++)
#pragma unroll
            for (int i = 0; i < 4; i++) {
                int gm = bm + wm + fm * 16 + rowmap[i];
                int gn = wn + fn * 16 + j;
                if (gm < SSP)
                    outv[obase + (size_t)gm * 64 + gn] = (float)(acc[fm][fn][i] + (double)bias[c0 + gn]);
            }
}

// -- value GEMM, BK=32: full 256 ch, nb batches; BM=128/BN=64 ------------------
__global__ __launch_bounds__(256)
void value2_mgemm(const float* __restrict__ s0, const float* __restrict__ s1,
                  const float* __restrict__ s2, const float* __restrict__ s3,
                  int b0, const float* __restrict__ W, const float* __restrict__ bias,
                  float* __restrict__ outv)
{
    __shared__ double As[32][130];
    __shared__ double Bs[32][67];
    int bm = blockIdx.x * 128;
    int bn = blockIdx.y * 64;
    int b = b0 + blockIdx.z;
    size_t obase = (size_t)blockIdx.z * SSP * 256;
    int tid = threadIdx.x;
    int lane = tid & 63, wave = tid >> 6;
    int wm = (wave >> 1) * 64, wn = (wave & 1) * 32;
    int j = lane & 15, q = lane >> 4;
    int rowmap[4];
    mfma_rowmap(lane, rowmap);
    int ra = tid & 127, ka0 = tid >> 7;
    const float* sbA; int hwA, sA;
    {
        int t = bm + ra; if (t > SSP - 1) t = SSP - 1;
        if (t < 10000)      { sbA = s0; hwA = 10000; sA = t; }
        else if (t < 12500) { sbA = s1; hwA = 2500;  sA = t - 10000; }
        else if (t < 13125) { sbA = s2; hwA = 625;   sA = t - 12500; }
        else                { sbA = s3; hwA = 169;   sA = t - 13125; }
    }
    int kb = tid & 31, rb0 = tid >> 5;
    v4d acc[4][2];
#pragma unroll
    for (int fm = 0; fm < 4; fm++)
#pragma unroll
        for (int fn = 0; fn < 2; fn++)
#pragma unroll
            for (int i = 0; i < 4; i++) acc[fm][fn][i] = 0.0;

    for (int k0 = 0; k0 < 256; k0 += 32) {
#pragma unroll
        for (int pp = 0; pp < 16; pp++) {
            int kaa = ka0 + pp * 2;
            As[kaa][ra] = (double)sbA[(size_t)(b * 256 + k0 + kaa) * hwA + sA];
        }
#pragma unroll
        for (int pp = 0; pp < 8; pp++) {
            int rb = rb0 + pp * 8;
            Bs[kb][rb] = (double)W[(size_t)(bn + rb) * 256 + k0 + kb];
        }
        __syncthreads();
#pragma unroll
        for (int kst = 0; kst < 8; kst++) {
            int krow = kst * 4 + q;
            double a0 = As[krow][wm + j];
            double a1 = As[krow][wm + 16 + j];
            double a2 = As[krow][wm + 32 + j];
            double a3 = As[krow][wm + 48 + j];
            double b0v = Bs[krow][wn + j];
            double b1v = Bs[krow][wn + 16 + j];
            acc[0][0] = __builtin_amdgcn_mfma_f64_16x16x4f64(a0, b0v, acc[0][0], 0, 0, 0);
            acc[0][1] = __builtin_amdgcn_mfma_f64_16x16x4f64(a0, b1v, acc[0][1], 0, 0, 0);
            acc[1][0] = __builtin_amdgcn_mfma_f64_16x16x4f64(a1, b0v, acc[1][0], 0, 0, 0);
            acc[1][1] = __builtin_amdgcn_mfma_f64_16x16x4f64(a1, b1v, acc[1][1], 0, 0, 0);
            acc[2][0] = __builtin_amdgcn_mfma_f64_16x16x4f64(a2, b0v, acc[2][0], 0, 0, 0);
            acc[2][1] = __builtin_amdgcn_mfma_f64_16x16x4f64(a2, b1v, acc[2][1], 0, 0, 0);
            acc[3][0] = __builtin_amdgcn_mfma_f64_16x16x4f64(a3, b0v, acc[3][0], 0, 0, 0);
            acc[3][1] = __builtin_amdgcn_mfma_f64_16x16x4f64(a3, b1v, acc[3][1], 0, 0, 0);
        }
        __syncthreads();
    }
#pragma unroll
    for (int fm = 0; fm < 4; fm++)
#pragma unroll
        for (int fn = 0; fn < 2; fn++)
#pragma unroll
            for (int i = 0; i < 4; i++) {
                int gm = bm + wm + fm * 16 + rowmap[i];
                int gn = bn + wn + fn * 16 + j;
                if (gm < SSP)
                    outv[obase + (size_t)gm * 256 + gn] = (float)(acc[fm][fn][i] + (double)bias[gn]);
            }
}

// ---------------- MHA v3: 12 rows x 1 head per block, probs in registers ------
// grid (200, 8), 384 thr = 12 groups x 32 lanes; one q-row per group.
// K staged in 150-token chunks (LDS 21.4 KB vs 70.6 KB before -> 5 blocks/CU).
// Scores bit-identical (same d-order); PV chains bit-identical to r5 (t&3 asc).
__global__ __launch_bounds__(384)
void mha12(const float* __restrict__ qk, const float* __restrict__ vbuf,
           float* __restrict__ mha)
{
    int bx = blockIdx.x;
    int b = bx / 25;
    int row0 = b * 300 + (bx % 25) * 12;
    int h = blockIdx.y;
    const double scale = 0.17677669529663687;
    __shared__ float Ks[150][33];
    __shared__ float Qs[12][33];
    int tid = threadIdx.x;
    int r = tid >> 5, lane = tid & 31;
    Qs[r][lane] = qk[(size_t)(row0 + r) * 512 + h * 32 + lane];
    double p[10];                    // token t = 150c + 32it + lane
    double mx = -1e300;
    for (int c = 0; c < 2; c++) {
        __syncthreads();             // Ks reuse / Qs visibility
        for (int e = tid; e < 150 * 32; e += 384) {
            int jj = e >> 5, d = e & 31;
            Ks[jj][d] = qk[(size_t)(b * 300 + c * 150 + jj) * 512 + 256 + h * 32 + d];
        }
        __syncthreads();
#pragma unroll
        for (int it = 0; it < 5; it++) {
            int jl = lane + it * 32;
            double t = 0.;
            if (jl < 150) {
#pragma unroll
                for (int d = 0; d < 32; d++) t += (double)Qs[r][d] * (double)Ks[jl][d];
                mx = fmax(mx, t);
            }
            p[c * 5 + it] = t;
        }
    }
#pragma unroll
    for (int o = 16; o > 0; o >>= 1) mx = fmax(mx, __shfl_xor(mx, o));
    double psum = 0.;
#pragma unroll
    for (int c = 0; c < 2; c++)
#pragma unroll
        for (int it = 0; it < 5; it++) {
            int jl = lane + it * 32;
            double e = 0.;
            if (jl < 150) { e = exp((p[c * 5 + it] - mx) * scale); psum += e; }
            p[c * 5 + it] = e;
        }
#pragma unroll
    for (int o = 16; o > 0; o >>= 1) psum += __shfl_xor(psum, o);
    double inv = 1.0 / psum;
    // PV: broadcast probs via shuffle (fp64 preserved); chains by t&3, t asc.
    const float* vp = vbuf + (size_t)(b * 300) * 256 + h * 32 + lane;
    double o0 = 0., o1 = 0., o2 = 0., o3 = 0.;
#pragma unroll
    for (int c = 0; c < 2; c++)
#pragma unroll
        for (int it = 0; it < 5; it++)
#pragma unroll
            for (int src = 0; src < 32; src++) {
                if (it == 4 && src >= 22) continue;   // 32*4+src < 150
                int t = 150 * c + 32 * it + src;
                double pv = __shfl(p[c * 5 + it], src, 32);
                double v = (double)vp[(size_t)t * 256];
                if ((t & 3) == 0) o0 += pv * v;
                else if ((t & 3) == 1) o1 += pv * v;
                else if ((t & 3) == 2) o2 += pv * v;
                else o3 += pv * v;
            }
    double o = ((o0 + o1) + (o2 + o3)) * inv;
    mha[(size_t)(row0 + r) * 256 + h * 32 + lane] = (float)o;
}

// ---------------- small-N GEMMs, fp64 math ------------------------------------
__global__ __launch_bounds__(256)
void gemm_small_qe(const float* __restrict__ qe, const float* __restrict__ W,
                   const float* __restrict__ bias, float* __restrict__ out, int N, int M)
{
    int t = blockIdx.x * 256 + threadIdx.x;
    if (t >= M * N) return;
    int row = t / N, n = t % N;
    const float* a = qe + (size_t)(row % 300) * 512;
    const float* w = W + (size_t)n * 256;
    double s = 0.0;
    for (int k = 0; k < 256; k++) s += (double)a[k] * (double)w[k];
    out[t] = (float)(s + (double)bias[n]);
}
__global__ __launch_bounds__(256)
void gemm_smallN(const float* __restrict__ A, int lda, const float* __restrict__ W,
                 const float* __restrict__ bias, float* __restrict__ out, int N, int M)
{
    int t = blockIdx.x * 256 + threadIdx.x;
    if (t >= M * N) return;
    int row = t / N, n = t % N;
    const float* a = A + (size_t)row * lda;
    const float* w = W + (size_t)n * 256;
    double s = 0.0;
    for (int k = 0; k < 256; k++) s += (double)a[k] * (double)w[k];
    out[t] = (float)(s + (double)bias[n]);
}

// ---------------- tgt init (fp64 residual stream) -----------------------------
__global__ __launch_bounds__(256)
void init_tgt(const float* __restrict__ qe, double* __restrict__ tgt)
{
    int row = blockIdx.x, c = threadIdx.x;
    size_t i = (size_t)row * 256 + c;
    tgt[i] = (row < NROW) ? (double)qe[(size_t)(row % 300) * 512 + 256 + c] : 0.0;
}

__global__ void add_q(const double* __restrict__ tgt, const float* __restrict__ qe,
                      float* __restrict__ qin)
{
    int row = blockIdx.x, c = threadIdx.x;
    size_t i = (size_t)row * 256 + c;
    qin[i] = (float)(tgt[i] + (double)qe[(size_t)(row % 300) * 512 + c]);
}

// ---------------- fused residual-add + LayerNorm, fp64 math -------------------
__global__ __launch_bounds__(256)
void add_ln(double* __restrict__ tgt, const float* __restrict__ br,
            const float* __restrict__ w, const float* __restrict__ b,
            float* __restrict__ hs_out)
{
    int row = blockIdx.x, c = threadIdx.x;
    size_t idx = (size_t)row * 256 + c;
    double v = tgt[idx] + (double)br[idx];
    double s = v, s2 = v * v;
#pragma unroll
    for (int o = 32; o > 0; o >>= 1) { s += __shfl_xor(s, o); s2 += __shfl_xor(s2, o); }
    __shared__ double rs[4], rs2[4];
    int wv = c >> 6;
    if ((c & 63) == 0) { rs[wv] = s; rs2[wv] = s2; }
    __syncthreads();
    double S = rs[0] + rs[1] + rs[2] + rs[3];
    double S2 = rs2[0] + rs2[1] + rs2[2] + rs2[3];
    double mean = S * (1.0 / 256.0);
    double var = S2 * (1.0 / 256.0) - mean * mean;
    double o = (v - mean) / sqrt(var + 1e-5) * (double)w[c] + (double)b[c];
    tgt[idx] = o;
    if (hs_out) hs_out[idx] = (float)o;
}

// ---------------- attention-weight softmax over 16 per (row,h), fp64 ----------
__global__ __launch_bounds__(256)
void aw_softmax(float* __restrict__ buf)
{
    int t = blockIdx.x * 256 + threadIdx.x;
    if (t >= NROW * 8) return;
    int row = t >> 3, h = t & 7;
    float* p = buf + (size_t)row * 128 + h * 16;
    double mx = -1e300, e[16];
#pragma unroll
    for (int j = 0; j < 16; j++) mx = fmax(mx, (double)p[j]);
    double s = 0.;
#pragma unroll
    for (int j = 0; j < 16; j++) { e[j] = exp((double)p[j] - mx); s += e[j]; }
    double inv = 1.0 / s;
#pragma unroll
    for (int j = 0; j < 16; j++) p[j] = (float)(e[j] * inv);
}

// ------ OLD sampler (fallback): value 2 batches x 64 ch slice -----------------
__global__ __launch_bounds__(64)
void deform_sample(const float* __restrict__ value, int h0,
                   const float* __restrict__ offb, const float* __restrict__ awsm,
                   const double* __restrict__ ref, float* __restrict__ out, int row0)
{
    int row = row0 + blockIdx.x;
    int hl = threadIdx.x >> 5, d = threadIdx.x & 31;
    int h = h0 + hl;
    double rx = ref[row * 4 + 0], ry = ref[row * 4 + 1];
    double rw = ref[row * 4 + 2], rh = ref[row * 4 + 3];
    const float* offr = offb + (size_t)row * 256;
    const float* awr = awsm + (size_t)row * 128 + h * 16;
    size_t vbase = (size_t)(blockIdx.x / 300) * SSP * 64 + hl * 32 + d;
    const int LH[4] = {100, 50, 25, 13};
    const int LW[4] = {100, 50, 25, 13};
    const int LS[4] = {0, 10000, 12500, 13125};
    double acc = 0.;
#pragma unroll
    for (int l = 0; l < 4; l++) {
        int Hh = LH[l], Ww = LW[l], st = LS[l];
#pragma unroll
        for (int p = 0; p < 4; p++) {
            double ox = (double)offr[(h * 32) + l * 8 + p * 2 + 0];
            double oy = (double)offr[(h * 32) + l * 8 + p * 2 + 1];
            double aw = (double)awr[l * 4 + p];
            double x = (rx + ox * 0.125 * rw) * Ww - 0.5;
            double y = (ry + oy * 0.125 * rh) * Hh - 0.5;
            double xf = floor(x), yf = floor(y);
            double dx = x - xf, dy = y - yf;
            int x0 = (int)xf, y0 = (int)yf;
            double w00 = (1 - dx) * (1 - dy), w10 = dx * (1 - dy);
            double w01 = (1 - dx) * dy, w11 = dx * dy;
#define CORN(X, Y, W)                                                              \
            if ((unsigned)(X) < (unsigned)Ww && (unsigned)(Y) < (unsigned)Hh)      \
                acc += (W) * aw * (double)value[vbase + (size_t)(st + (Y) * Ww + (X)) * 64];
            CORN(x0, y0, w00) CORN(x0 + 1, y0, w10) CORN(x0, y0 + 1, w01) CORN(x0 + 1, y0 + 1, w11)
#undef CORN
        }
    }
    out[(size_t)row * 256 + h * 32 + d] = (float)acc;
}

// ------ NEW sampler: value [bslot][token][256], all 8 heads per block ---------
__global__ __launch_bounds__(256)
void deform_sample2(const float* __restrict__ value,
                    const float* __restrict__ offb, const float* __restrict__ awsm,
                    const double* __restrict__ ref, float* __restrict__ out, int row0)
{
    int row = row0 + blockIdx.x;
    int h = threadIdx.x >> 5, d = threadIdx.x & 31;
    double rx = ref[row * 4 + 0], ry = ref[row * 4 + 1];
    double rw = ref[row * 4 + 2], rh = ref[row * 4 + 3];
    const float* offr = offb + (size_t)row * 256;
    const float* awr = awsm + (size_t)row * 128 + h * 16;
    size_t vbase = (size_t)(blockIdx.x / 300) * SSP * 256 + h * 32 + d;
    const int LH[4] = {100, 50, 25, 13};
    const int LW[4] = {100, 50, 25, 13};
    const int LS[4] = {0, 10000, 12500, 13125};
    double acc = 0.;
#pragma unroll
    for (int l = 0; l < 4; l++) {
        int Hh = LH[l], Ww = LW[l], st = LS[l];
#pragma unroll
        for (int p = 0; p < 4; p++) {
            double ox = (double)offr[(h * 32) + l * 8 + p * 2 + 0];
            double oy = (double)offr[(h * 32) + l * 8 + p * 2 + 1];
            double aw = (double)awr[l * 4 + p];
            double x = (rx + ox * 0.125 * rw) * Ww - 0.5;
            double y = (ry + oy * 0.125 * rh) * Hh - 0.5;
            double xf = floor(x), yf = floor(y);
            double dx = x - xf, dy = y - yf;
            int x0 = (int)xf, y0 = (int)yf;
            double w00 = (1 - dx) * (1 - dy), w10 = dx * (1 - dy);
            double w01 = (1 - dx) * dy, w11 = dx * dy;
#define CORN(X, Y, W)                                                              \
            if ((unsigned)(X) < (unsigned)Ww && (unsigned)(Y) < (unsigned)Hh)      \
                acc += (W) * aw * (double)value[vbase + (size_t)(st + (Y) * Ww + (X)) * 256];
            CORN(x0, y0, w00) CORN(x0 + 1, y0, w10) CORN(x0, y0 + 1, w01) CORN(x0 + 1, y0 + 1, w11)
#undef CORN
        }
    }
    out[(size_t)row * 256 + h * 32 + d] = (float)acc;
}

// ---------------- ref init / update (fp64 state, fp32 refs out) ---------------
__global__ void ref_init(const float* __restrict__ lin2, const float* __restrict__ bb,
                         double* __restrict__ ref)
{
    int t = blockIdx.x * 256 + threadIdx.x;
    if (t >= NROW) return;
#pragma unroll
    for (int j = 0; j < 2; j++) {
        double r2 = sigd((double)lin2[t * 2 + j]);
        ref[t * 4 + j] = sigd((double)bb[t * 4 + j] + invsigd(r2));
    }
    ref[t * 4 + 2] = sigd((double)bb[t * 4 + 2]);
    ref[t * 4 + 3] = sigd((double)bb[t * 4 + 3]);
}
__global__ void ref_update(const float* __restrict__ bb, double* __restrict__ ref,
                           float* __restrict__ refs_out)
{
    int t = blockIdx.x * 256 + threadIdx.x;
    if (t >= NROW * 4) return;
    double nv = sigd((double)bb[t] + invsigd(ref[t]));
    ref[t] = nv;
    refs_out[t] = (float)nv;
}

// =============================== launcher =====================================
extern "C" void kernel_launch(void* const* d_in, const int* in_sizes, int n_in,
                              void* d_out, int out_size, void* d_ws, size_t ws_size,
                              hipStream_t stream)
{
    const float* src0 = (const float*)d_in[0];
    const float* src1 = (const float*)d_in[2];
    const float* src2 = (const float*)d_in[4];
    const float* src3 = (const float*)d_in[6];
    const float* qe = (const float*)d_in[8];
    const float* ref_w = (const float*)d_in[9];
    const float* ref_b = (const float*)d_in[10];
    const float* sa_in_w = (const float*)d_in[11];
    const float* sa_in_b = (const float*)d_in[12];
    const float* sa_out_w = (const float*)d_in[13];
    const float* sa_out_b = (const float*)d_in[14];
    const float* off_w = (const float*)d_in[15];
    const float* off_b = (const float*)d_in[16];
    const float* aw_w = (const float*)d_in[17];
    const float* aw_b = (const float*)d_in[18];
    const float* val_w = (const float*)d_in[19];
    const float* val_b = (const float*)d_in[20];
    const float* cao_w = (const float*)d_in[21];
    const float* cao_b = (const float*)d_in[22];
    const float* ln1_w = (const float*)d_in[23];
    const float* ln1_b = (const float*)d_in[24];
    const float* ln2_w = (const float*)d_in[25];
    const float* ln2_b = (const float*)d_in[26];
    const float* ln3_w = (const float*)d_in[27];
    const float* ln3_b = (const float*)d_in[28];
    const float* ff1_w = (const float*)d_in[29];
    const float* ff1_b = (const float*)d_in[30];
    const float* ff2_w = (const float*)d_in[31];
    const float* ff2_b = (const float*)d_in[32];
    const float* bb_w1 = (const float*)d_in[33];
    const float* bb_b1 = (const float*)d_in[34];
    const float* bb_w2 = (const float*)d_in[35];
    const float* bb_b2 = (const float*)d_in[36];
    const float* bb_w3 = (const float*)d_in[37];
    const float* bb_b3 = (const float*)d_in[38];
    const float* cls_w = (const float*)d_in[39];
    const float* cls_b = (const float*)d_in[40];

    char* wsp = (char*)d_ws;
    size_t off_ws = 0;
    auto alloc = [&](size_t bytes) -> char* {
        char* p = wsp + off_ws;
        off_ws += (bytes + 255) & ~(size_t)255;
        return p;
    };
    double* tgt  = (double*)alloc((size_t)NROWP * 256 * 8);  // 4.98 MB fp64 residual
    char* bigA = alloc((size_t)NROWP * 512 * 4);             // 4.98 union
    float* qk   = (float*)bigA;
    float* ffnh = (float*)bigA;
    float* offb = (float*)bigA;
    float* awb  = (float*)(bigA + (size_t)NROWP * 256 * 4);
    char* bufB = alloc((size_t)NROWP * 256 * 4);             // 2.49 union
    float* vbuf = (float*)bufB;
    float* samp = (float*)bufB;
    float* bh1  = (float*)bufB;
    float* bb4   = (float*)alloc((size_t)NROWP * 4 * 4);
    double* refb = (double*)alloc((size_t)NROWP * 4 * 8);
    float* rlin2 = (float*)alloc((size_t)NROWP * 2 * 4);
    size_t val_off = off_ws;
    float* proj = (float*)alloc((size_t)NROWP * 256 * 4);    // 2.49
    char* bufC  = alloc((size_t)NROWP * 256 * 4);            // 2.49 union
    float* qin = (float*)bufC;
    float* mhab = (float*)bufC;
    float* bh2 = (float*)bufC;
    float* valueBig = proj;   // value region spans proj, bufC, and ws tail

    // path selection by available workspace beyond val_off
    size_t avail = ws_size > val_off ? ws_size - val_off : 0;
    size_t vbytes = (size_t)SSP * 256 * 4;                   // 13.6 MB per batch
    int nb = 0;
    if (avail >= 8 * vbytes + 4096) nb = 8;
    else if (avail >= 4 * vbytes + 4096) nb = 4;
    else if (avail >= 2 * vbytes + 4096) nb = 2;
    else if (avail >= 1 * vbytes + 4096) nb = 1;
    // nb==0 -> fallback 64-ch-slice path (needs 6.81 MB at val_off, proven safe)

    float* out_f = (float*)d_out;
    float* hs_out = out_f;                                   // 6 * 614400
    float* refs_out = out_f + (size_t)6 * 614400;            // 6 * 9600
    float* log_out = refs_out + (size_t)6 * 9600;            // 6 * 194400

    // ---- setup ----
    init_tgt<<<NROWP, 256, 0, stream>>>(qe, tgt);
    gemm_small_qe<<<(NROW * 2 + 255) / 256, 256, 0, stream>>>(qe, ref_w, ref_b, rlin2, 2, NROW);
    launch_m<double, true, false>(stream, tgt, 256, bb_w1, 256, bb_b1, bh1, 256, NROW, 256, 256);
    launch_m<float, true, false>(stream, bh1, 256, bb_w2, 256, bb_b2, proj, 256, NROW, 256, 256);
    gemm_smallN<<<(NROW * 4 + 255) / 256, 256, 0, stream>>>(proj, 256, bb_w3, bb_b3, bb4, 4, NROW);
    ref_init<<<(NROW + 255) / 256, 256, 0, stream>>>(rlin2, bb4, refb);

    for (int i = 0; i < 6; i++) {
        // ---- self attention ----
        add_q<<<NROW, 256, 0, stream>>>(tgt, qe, qin);
        launch_m<float, false, false>(stream, qin, 256, sa_in_w + (size_t)i * 196608, 256,
                                      sa_in_b + i * 768, qk, 512, NROW, 512, 256);
        launch_m<double, false, false>(stream, tgt, 256, sa_in_w + (size_t)i * 196608 + 131072, 256,
                                       sa_in_b + i * 768 + 512, vbuf, 256, NROW, 256, 256);
        mha12<<<dim3(200, 8), 384, 0, stream>>>(qk, vbuf, mhab);
        launch_m<float, false, false>(stream, mhab, 256, sa_out_w + (size_t)i * 65536, 256,
                                      sa_out_b + i * 256, proj, 256, NROW, 256, 256);
        add_ln<<<NROW, 256, 0, stream>>>(tgt, proj, ln2_w + i * 256, ln2_b + i * 256, nullptr);

        // ---- deformable cross attention ----
        add_q<<<NROW, 256, 0, stream>>>(tgt, qe, qin);
        launch_m<float, false, false>(stream, qin, 256, off_w + (size_t)i * 65536, 256,
                                      off_b + i * 256, offb, 256, NROW, 256, 256);
        launch_m<float, false, false>(stream, qin, 256, aw_w + (size_t)i * 32768, 256,
                                      aw_b + i * 128, awb, 128, NROW, 128, 256);
        aw_softmax<<<(NROW * 8 + 255) / 256, 256, 0, stream>>>(awb);
        if (nb > 0) {
            for (int bg = 0; bg < 8 / nb; bg++) {
                value2_mgemm<<<dim3((SSP + 127) / 128, 4, nb), 256, 0, stream>>>(
                    src0, src1, src2, src3, bg * nb, val_w + (size_t)i * 65536, val_b + i * 256,
                    valueBig);
                deform_sample2<<<nb * 300, 256, 0, stream>>>(valueBig, offb, awb, refb,
                                                             samp, bg * nb * 300);
            }
        } else {
            for (int s = 0; s < 4; s++) {
                for (int bg = 0; bg < 4; bg++) {
                    value_mgemm<<<dim3((SSP + 63) / 64, 2), 256, 0, stream>>>(
                        src0, src1, src2, src3, bg * 2, val_w + (size_t)i * 65536, val_b + i * 256,
                        valueBig, s * 64);
                    deform_sample<<<600, 64, 0, stream>>>(valueBig, s * 2, offb, awb, refb,
                                                          samp, bg * 600);
                }
            }
        }
        launch_m<float, false, false>(stream, samp, 256, cao_w + (size_t)i * 65536, 256,
                                      cao_b + i * 256, proj, 256, NROW, 256, 256);
        add_ln<<<NROW, 256, 0, stream>>>(tgt, proj, ln1_w + i * 256, ln1_b + i * 256, nullptr);

        // ---- FFN, hidden split 2x512 into ffnh(bigA) ----
        launch_m<double, true, false>(stream, tgt, 256, ff1_w + (size_t)i * 262144, 256,
                                      ff1_b + i * 1024, ffnh, 512, NROW, 512, 256);
        launch_m<float, false, false>(stream, ffnh, 512, ff2_w + (size_t)i * 262144, 1024,
                                      ff2_b + i * 256, proj, 256, NROW, 256, 512);
        launch_m<double, true, false>(stream, tgt, 256, ff1_w + (size_t)i * 262144 + 512 * 256, 256,
                                      ff1_b + i * 1024 + 512, ffnh, 512, NROW, 512, 256);
        launch_m<float, false, true>(stream, ffnh, 512, ff2_w + (size_t)i * 262144 + 512, 1024,
                                     nullptr, proj, 256, NROW, 256, 512);
        add_ln<<<NROW, 256, 0, stream>>>(tgt, proj, ln3_w + i * 256, ln3_b + i * 256,
                                         hs_out + (size_t)i * 614400);

        // ---- bbox refinement: bh1(bufB), bh2(bufC) ----
        launch_m<double, true, false>(stream, tgt, 256, bb_w1 + (size_t)(i + 1) * 65536, 256,
                                      bb_b1 + (i + 1) * 256, bh1, 256, NROW, 256, 256);
        launch_m<float, true, false>(stream, bh1, 256, bb_w2 + (size_t)(i + 1) * 65536, 256,
                                     bb_b2 + (i + 1) * 256, bh2, 256, NROW, 256, 256);
        gemm_smallN<<<(NROW * 4 + 255) / 256, 256, 0, stream>>>(
            bh2, 256, bb_w3 + (size_t)(i + 1) * 1024, bb_b3 + (i + 1) * 4, bb4, 4, NROW);
        ref_update<<<(NROW * 4 + 255) / 256, 256, 0, stream>>>(bb4, refb, refs_out + (size_t)i * 9600);

        // ---- logits ----
        launch_m<double, false, false>(stream, tgt, 256, cls_w + (size_t)(i + 1) * 20736, 256,
                                       cls_b + (i + 1) * 81, log_out + (size_t)i * 194400,
                                       81, NROW, 81, 256);
    }
}

// Round 7
// 5463.589 us; speedup vs baseline: 3.3256x; 1.0273x over previous
//
#include <hip/hip_runtime.h>
#include <cstdint>

#define SSP   13294      // total spatial tokens (100^2+50^2+25^2+13^2)
#define NROW  2400       // B*NQ
#define NROWP 2432

typedef double v4d __attribute__((ext_vector_type(4)));

__device__ __forceinline__ double sigd(double x) { return 1.0 / (1.0 + exp(-x)); }
__device__ __forceinline__ double invsigd(double x) {
    x = fmin(fmax(x, 0.0), 1.0);
    return log(fmax(x, 1e-5) / fmax(1.0 - x, 1e-5));
}
__device__ __forceinline__ double rdA(const float* a, size_t k) { return (double)a[k]; }
__device__ __forceinline__ double rdA(const double* a, size_t k) { return a[k]; }

// Self-calibrating probe for the f64 MFMA C/D row mapping (verified working r2).
__device__ __forceinline__ void mfma_rowmap(int lane, int* rm) {
    v4d c = {0., 0., 0., 0.};
    double a = (double)(lane & 15);
    c = __builtin_amdgcn_mfma_f64_16x16x4f64(a, 0.25, c, 0, 0, 0);
#pragma unroll
    for (int r = 0; r < 4; r++) rm[r] = (int)(c[r] + 0.5);
}

// ---- fp64 MFMA GEMM, BK=32: C (+)= relu?(A @ W^T + bias) --------------------
// QF: A-read fused with qpos add (qin = (float)(tgt + qe)), bit-identical to
// the old add_q + float-buffer path.
template<typename TA, bool RELU, bool ACC, bool QF>
__global__ __launch_bounds__(256)
void mgemm(const TA* __restrict__ A, int lda, const float* __restrict__ qpos,
           const float* __restrict__ W, int ldb,
           const float* __restrict__ bias,
           float* __restrict__ C, int ldc,
           int M, int N, int K)
{
    __shared__ double As[32][67];
    __shared__ double Bs[32][67];
    int bm = blockIdx.x * 64, bn = blockIdx.y * 64;
    int tid = threadIdx.x;
    int lane = tid & 63, wave = tid >> 6;
    int wm = (wave >> 1) * 32, wn = (wave & 1) * 32;
    int j = lane & 15, q = lane >> 4;
    int kk = tid & 31, r0 = tid >> 5;
    int rowmap[4];
    mfma_rowmap(lane, rowmap);
    v4d acc[2][2];
#pragma unroll
    for (int fm = 0; fm < 2; fm++)
#pragma unroll
        for (int fn = 0; fn < 2; fn++)
#pragma unroll
            for (int i = 0; i < 4; i++) acc[fm][fn][i] = 0.0;

    for (int k0 = 0; k0 < K; k0 += 32) {
#pragma unroll
        for (int rr = 0; rr < 8; rr++) {
            int r = r0 + rr * 8;
            int am = bm + r; if (am > M - 1) am = M - 1;
            double av = rdA(A, (size_t)am * lda + k0 + kk);
            if (QF) av = (double)(float)(av + (double)qpos[(size_t)(am % 300) * 512 + k0 + kk]);
            As[kk][r] = av;
            int wn_ = bn + r; if (wn_ > N - 1) wn_ = N - 1;
            Bs[kk][r] = (double)W[(size_t)wn_ * ldb + k0 + kk];
        }
        __syncthreads();
#pragma unroll
        for (int kst = 0; kst < 8; kst++) {
            int krow = kst * 4 + q;
            double a0 = As[krow][wm + j];
            double a1 = As[krow][wm + 16 + j];
            double b0 = Bs[krow][wn + j];
            double b1 = Bs[krow][wn + 16 + j];
            acc[0][0] = __builtin_amdgcn_mfma_f64_16x16x4f64(a0, b0, acc[0][0], 0, 0, 0);
            acc[0][1] = __builtin_amdgcn_mfma_f64_16x16x4f64(a0, b1, acc[0][1], 0, 0, 0);
            acc[1][0] = __builtin_amdgcn_mfma_f64_16x16x4f64(a1, b0, acc[1][0], 0, 0, 0);
            acc[1][1] = __builtin_amdgcn_mfma_f64_16x16x4f64(a1, b1, acc[1][1], 0, 0, 0);
        }
        __syncthreads();
    }
#pragma unroll
    for (int fm = 0; fm < 2; fm++)
#pragma unroll
        for (int fn = 0; fn < 2; fn++)
#pragma unroll
            for (int i = 0; i < 4; i++) {
                int gm = bm + wm + fm * 16 + rowmap[i];
                int gn = bn + wn + fn * 16 + j;
                if (gm < M && gn < N) {
                    double v = acc[fm][fn][i] + (bias ? (double)bias[gn] : 0.0);
                    if (ACC) v += (double)C[(size_t)gm * ldc + gn];
                    if (RELU) v = fmax(v, 0.0);
                    C[(size_t)gm * ldc + gn] = (float)v;
                }
            }
}

template<typename TA, bool RELU, bool ACC>
static void launch_m(hipStream_t st, const TA* A, int lda, const float* W, int ldb,
                     const float* bias, float* C, int ldc, int M, int N, int K)
{
    dim3 grid((M + 63) / 64, (N + 63) / 64, 1);
    mgemm<TA, RELU, ACC, false><<<grid, 256, 0, st>>>(A, lda, nullptr, W, ldb, bias, C, ldc, M, N, K);
}
static void launch_mq(hipStream_t st, const double* A, int lda, const float* qe,
                      const float* W, int ldb, const float* bias, float* C, int ldc,
                      int M, int N, int K)
{
    dim3 grid((M + 63) / 64, (N + 63) / 64, 1);
    mgemm<double, false, false, true><<<grid, 256, 0, st>>>(A, lda, qe, W, ldb, bias, C, ldc, M, N, K);
}

// -- OLD value GEMM (fallback), 64-ch slice, 2 batches, BK=16 ------------------
__global__ __launch_bounds__(256)
void value_mgemm(const float* __restrict__ s0, const float* __restrict__ s1,
                 const float* __restrict__ s2, const float* __restrict__ s3,
                 int b0, const float* __restrict__ W, const float* __restrict__ bias,
                 float* __restrict__ outv, int c0)
{
    __shared__ double As[16][66];
    __shared__ double Bs[16][66];
    int bm = blockIdx.x * 64;
    int b = b0 + blockIdx.y;
    size_t obase = (size_t)blockIdx.y * SSP * 64;
    int tid = threadIdx.x;
    int lane = tid & 63, wave = tid >> 6;
    int wm = (wave >> 1) * 32, wn = (wave & 1) * 32;
    int j = lane & 15, q = lane >> 4;
    int ka = tid >> 4, ra0 = tid & 15;
    int kb = tid & 15, rb0 = tid >> 4;
    int rowmap[4];
    mfma_rowmap(lane, rowmap);
    v4d acc[2][2];
#pragma unroll
    for (int fm = 0; fm < 2; fm++)
#pragma unroll
        for (int fn = 0; fn < 2; fn++)
#pragma unroll
            for (int i = 0; i < 4; i++) acc[fm][fn][i] = 0.0;

    for (int k0 = 0; k0 < 256; k0 += 16) {
#pragma unroll
        for (int rr = 0; rr < 4; rr++) {
            int ra = ra0 + rr * 16;
            int t = bm + ra; if (t > SSP - 1) t = SSP - 1;
            const float* sb; int hw, s;
            if (t < 10000)      { sb = s0; hw = 10000; s = t; }
            else if (t < 12500) { sb = s1; hw = 2500;  s = t - 10000; }
            else if (t < 13125) { sb = s2; hw = 625;   s = t - 12500; }
            else                { sb = s3; hw = 169;   s = t - 13125; }
            As[ka][ra] = (double)sb[(size_t)(b * 256 + k0 + ka) * hw + s];
            int rb = rb0 + rr * 16;
            Bs[kb][rb] = (double)W[(size_t)(c0 + rb) * 256 + k0 + kb];
        }
        __syncthreads();
#pragma unroll
        for (int kst = 0; kst < 4; kst++) {
            int krow = kst * 4 + q;
            double a0 = As[krow][wm + j];
            double a1 = As[krow][wm + 16 + j];
            double b0v = Bs[krow][wn + j];
            double b1v = Bs[krow][wn + 16 + j];
            acc[0][0] = __builtin_amdgcn_mfma_f64_16x16x4f64(a0, b0v, acc[0][0], 0, 0, 0);
            acc[0][1] = __builtin_amdgcn_mfma_f64_16x16x4f64(a0, b1v, acc[0][1], 0, 0, 0);
            acc[1][0] = __builtin_amdgcn_mfma_f64_16x16x4f64(a1, b0v, acc[1][0], 0, 0, 0);
            acc[1][1] = __builtin_amdgcn_mfma_f64_16x16x4f64(a1, b1v, acc[1][1], 0, 0, 0);
        }
        __syncthreads();
    }
#pragma unroll
    for (int fm = 0; fm < 2; fm++)
#pragma unroll
        for (int fn = 0; fn < 2; fn++)
#pragma unroll
            for (int i = 0; i < 4; i++) {
                int gm = bm + wm + fm * 16 + rowmap[i];
                int gn = wn + fn * 16 + j;
                if (gm < SSP)
                    outv[obase + (size_t)gm * 64 + gn] = (float)(acc[fm][fn][i] + (double)bias[c0 + gn]);
            }
}

// -- value GEMM v3: BM=128, BN=128, BK=16; full 256 ch, nb batches -------------
// MFMA:staged-load ratio 4.0 (was 2.67). Per-output k-sequence identical to
// BK=32 version (k = k0+kst*4+q ascending by 4) -> bit-identical results.
__global__ __launch_bounds__(256, 2)
void value3_mgemm(const float* __restrict__ s0, const float* __restrict__ s1,
                  const float* __restrict__ s2, const float* __restrict__ s3,
                  int b0, const float* __restrict__ W, const float* __restrict__ bias,
                  float* __restrict__ outv)
{
    __shared__ double As[16][130];
    __shared__ double Bs[16][130];
    int bm = blockIdx.x * 128;
    int bn = blockIdx.y * 128;
    int b = b0 + blockIdx.z;
    size_t obase = (size_t)blockIdx.z * SSP * 256;
    int tid = threadIdx.x;
    int lane = tid & 63, wave = tid >> 6;
    int wm = (wave >> 1) * 64, wn = (wave & 1) * 64;
    int j = lane & 15, q = lane >> 4;
    int rowmap[4];
    mfma_rowmap(lane, rowmap);
    int ra = tid & 127, ka0 = tid >> 7;        // A: token ra, k rows ka0+2pp
    const float* sbA; int hwA, sA;
    {
        int t = bm + ra; if (t > SSP - 1) t = SSP - 1;
        if (t < 10000)      { sbA = s0; hwA = 10000; sA = t; }
        else if (t < 12500) { sbA = s1; hwA = 2500;  sA = t - 10000; }
        else if (t < 13125) { sbA = s2; hwA = 625;   sA = t - 12500; }
        else                { sbA = s3; hwA = 169;   sA = t - 13125; }
    }
    int kb = tid & 15, rb0 = tid >> 4;          // B: k col kb, rows rb0+16pp
    v4d acc[4][4];
#pragma unroll
    for (int fm = 0; fm < 4; fm++)
#pragma unroll
        for (int fn = 0; fn < 4; fn++)
#pragma unroll
            for (int i = 0; i < 4; i++) acc[fm][fn][i] = 0.0;

    for (int k0 = 0; k0 < 256; k0 += 16) {
#pragma unroll
        for (int pp = 0; pp < 8; pp++) {
            int kaa = ka0 + pp * 2;
            As[kaa][ra] = (double)sbA[(size_t)(b * 256 + k0 + kaa) * hwA + sA];
        }
#pragma unroll
        for (int pp = 0; pp < 8; pp++) {
            int rb = rb0 + pp * 16;
            Bs[kb][rb] = (double)W[(size_t)(bn + rb) * 256 + k0 + kb];
        }
        __syncthreads();
#pragma unroll
        for (int kst = 0; kst < 4; kst++) {
            int krow = kst * 4 + q;
            double a[4], bb[4];
#pragma unroll
            for (int m = 0; m < 4; m++) a[m] = As[krow][wm + m * 16 + j];
#pragma unroll
            for (int n = 0; n < 4; n++) bb[n] = Bs[krow][wn + n * 16 + j];
#pragma unroll
            for (int m = 0; m < 4; m++)
#pragma unroll
                for (int n = 0; n < 4; n++)
                    acc[m][n] = __builtin_amdgcn_mfma_f64_16x16x4f64(a[m], bb[n], acc[m][n], 0, 0, 0);
        }
        __syncthreads();
    }
#pragma unroll
    for (int fm = 0; fm < 4; fm++)
#pragma unroll
        for (int fn = 0; fn < 4; fn++)
#pragma unroll
            for (int i = 0; i < 4; i++) {
                int gm = bm + wm + fm * 16 + rowmap[i];
                int gn = bn + wn + fn * 16 + j;
                if (gm < SSP)
                    outv[obase + (size_t)gm * 256 + gn] = (float)(acc[fm][fn][i] + (double)bias[gn]);
            }
}

// ---------------- MHA v3: 12 rows x 1 head per block, probs in registers ------
__global__ __launch_bounds__(384)
void mha12(const float* __restrict__ qk, const float* __restrict__ vbuf,
           float* __restrict__ mha)
{
    int bx = blockIdx.x;
    int b = bx / 25;
    int row0 = b * 300 + (bx % 25) * 12;
    int h = blockIdx.y;
    const double scale = 0.17677669529663687;
    __shared__ float Ks[150][33];
    __shared__ float Qs[12][33];
    int tid = threadIdx.x;
    int r = tid >> 5, lane = tid & 31;
    Qs[r][lane] = qk[(size_t)(row0 + r) * 512 + h * 32 + lane];
    double p[10];                    // token t = 150c + 32it + lane
    double mx = -1e300;
    for (int c = 0; c < 2; c++) {
        __syncthreads();
        for (int e = tid; e < 150 * 32; e += 384) {
            int jj = e >> 5, d = e & 31;
            Ks[jj][d] = qk[(size_t)(b * 300 + c * 150 + jj) * 512 + 256 + h * 32 + d];
        }
        __syncthreads();
#pragma unroll
        for (int it = 0; it < 5; it++) {
            int jl = lane + it * 32;
            double t = 0.;
            if (jl < 150) {
#pragma unroll
                for (int d = 0; d < 32; d++) t += (double)Qs[r][d] * (double)Ks[jl][d];
                mx = fmax(mx, t);
            }
            p[c * 5 + it] = t;
        }
    }
#pragma unroll
    for (int o = 16; o > 0; o >>= 1) mx = fmax(mx, __shfl_xor(mx, o));
    double psum = 0.;
#pragma unroll
    for (int c = 0; c < 2; c++)
#pragma unroll
        for (int it = 0; it < 5; it++) {
            int jl = lane + it * 32;
            double e = 0.;
            if (jl < 150) { e = exp((p[c * 5 + it] - mx) * scale); psum += e; }
            p[c * 5 + it] = e;
        }
#pragma unroll
    for (int o = 16; o > 0; o >>= 1) psum += __shfl_xor(psum, o);
    double inv = 1.0 / psum;
    const float* vp = vbuf + (size_t)(b * 300) * 256 + h * 32 + lane;
    double o0 = 0., o1 = 0., o2 = 0., o3 = 0.;
#pragma unroll
    for (int c = 0; c < 2; c++)
#pragma unroll
        for (int it = 0; it < 5; it++)
#pragma unroll
            for (int src = 0; src < 32; src++) {
                if (it == 4 && src >= 22) continue;   // 32*4+src < 150
                int t = 150 * c + 32 * it + src;
                double pv = __shfl(p[c * 5 + it], src, 32);
                double v = (double)vp[(size_t)t * 256];
                if ((t & 3) == 0) o0 += pv * v;
                else if ((t & 3) == 1) o1 += pv * v;
                else if ((t & 3) == 2) o2 += pv * v;
                else o3 += pv * v;
            }
    double o = ((o0 + o1) + (o2 + o3)) * inv;
    mha[(size_t)(row0 + r) * 256 + h * 32 + lane] = (float)o;
}

// ---------------- small-N GEMMs, fp64 math ------------------------------------
__global__ __launch_bounds__(256)
void gemm_small_qe(const float* __restrict__ qe, const float* __restrict__ W,
                   const float* __restrict__ bias, float* __restrict__ out, int N, int M)
{
    int t = blockIdx.x * 256 + threadIdx.x;
    if (t >= M * N) return;
    int row = t / N, n = t % N;
    const float* a = qe + (size_t)(row % 300) * 512;
    const float* w = W + (size_t)n * 256;
    double s = 0.0;
    for (int k = 0; k < 256; k++) s += (double)a[k] * (double)w[k];
    out[t] = (float)(s + (double)bias[n]);
}
__global__ __launch_bounds__(256)
void gemm_smallN(const float* __restrict__ A, int lda, const float* __restrict__ W,
                 const float* __restrict__ bias, float* __restrict__ out, int N, int M)
{
    int t = blockIdx.x * 256 + threadIdx.x;
    if (t >= M * N) return;
    int row = t / N, n = t % N;
    const float* a = A + (size_t)row * lda;
    const float* w = W + (size_t)n * 256;
    double s = 0.0;
    for (int k = 0; k < 256; k++) s += (double)a[k] * (double)w[k];
    out[t] = (float)(s + (double)bias[n]);
}

// ---------------- tgt init (fp64 residual stream) -----------------------------
__global__ __launch_bounds__(256)
void init_tgt(const float* __restrict__ qe, double* __restrict__ tgt)
{
    int row = blockIdx.x, c = threadIdx.x;
    size_t i = (size_t)row * 256 + c;
    tgt[i] = (row < NROW) ? (double)qe[(size_t)(row % 300) * 512 + 256 + c] : 0.0;
}

// ---------------- fused residual-add + LayerNorm, fp64 math -------------------
__global__ __launch_bounds__(256)
void add_ln(double* __restrict__ tgt, const float* __restrict__ br,
            const float* __restrict__ w, const float* __restrict__ b,
            float* __restrict__ hs_out)
{
    int row = blockIdx.x, c = threadIdx.x;
    size_t idx = (size_t)row * 256 + c;
    double v = tgt[idx] + (double)br[idx];
    double s = v, s2 = v * v;
#pragma unroll
    for (int o = 32; o > 0; o >>= 1) { s += __shfl_xor(s, o); s2 += __shfl_xor(s2, o); }
    __shared__ double rs[4], rs2[4];
    int wv = c >> 6;
    if ((c & 63) == 0) { rs[wv] = s; rs2[wv] = s2; }
    __syncthreads();
    double S = rs[0] + rs[1] + rs[2] + rs[3];
    double S2 = rs2[0] + rs2[1] + rs2[2] + rs2[3];
    double mean = S * (1.0 / 256.0);
    double var = S2 * (1.0 / 256.0) - mean * mean;
    double o = (v - mean) / sqrt(var + 1e-5) * (double)w[c] + (double)b[c];
    tgt[idx] = o;
    if (hs_out) hs_out[idx] = (float)o;
}

// ---------------- attention-weight softmax over 16 per (row,h), fp64 ----------
__global__ __launch_bounds__(256)
void aw_softmax(float* __restrict__ buf)
{
    int t = blockIdx.x * 256 + threadIdx.x;
    if (t >= NROW * 8) return;
    int row = t >> 3, h = t & 7;
    float* p = buf + (size_t)row * 128 + h * 16;
    double mx = -1e300, e[16];
#pragma unroll
    for (int j = 0; j < 16; j++) mx = fmax(mx, (double)p[j]);
    double s = 0.;
#pragma unroll
    for (int j = 0; j < 16; j++) { e[j] = exp((double)p[j] - mx); s += e[j]; }
    double inv = 1.0 / s;
#pragma unroll
    for (int j = 0; j < 16; j++) p[j] = (float)(e[j] * inv);
}

// ------ OLD sampler (fallback): value 2 batches x 64 ch slice -----------------
__global__ __launch_bounds__(64)
void deform_sample(const float* __restrict__ value, int h0,
                   const float* __restrict__ offb, const float* __restrict__ awsm,
                   const double* __restrict__ ref, float* __restrict__ out, int row0)
{
    int row = row0 + blockIdx.x;
    int hl = threadIdx.x >> 5, d = threadIdx.x & 31;
    int h = h0 + hl;
    double rx = ref[row * 4 + 0], ry = ref[row * 4 + 1];
    double rw = ref[row * 4 + 2], rh = ref[row * 4 + 3];
    const float* offr = offb + (size_t)row * 256;
    const float* awr = awsm + (size_t)row * 128 + h * 16;
    size_t vbase = (size_t)(blockIdx.x / 300) * SSP * 64 + hl * 32 + d;
    const int LH[4] = {100, 50, 25, 13};
    const int LW[4] = {100, 50, 25, 13};
    const int LS[4] = {0, 10000, 12500, 13125};
    double acc = 0.;
#pragma unroll
    for (int l = 0; l < 4; l++) {
        int Hh = LH[l], Ww = LW[l], st = LS[l];
#pragma unroll
        for (int p = 0; p < 4; p++) {
            double ox = (double)offr[(h * 32) + l * 8 + p * 2 + 0];
            double oy = (double)offr[(h * 32) + l * 8 + p * 2 + 1];
            double aw = (double)awr[l * 4 + p];
            double x = (rx + ox * 0.125 * rw) * Ww - 0.5;
            double y = (ry + oy * 0.125 * rh) * Hh - 0.5;
            double xf = floor(x), yf = floor(y);
            double dx = x - xf, dy = y - yf;
            int x0 = (int)xf, y0 = (int)yf;
            double w00 = (1 - dx) * (1 - dy), w10 = dx * (1 - dy);
            double w01 = (1 - dx) * dy, w11 = dx * dy;
#define CORN(X, Y, W)                                                              \
            if ((unsigned)(X) < (unsigned)Ww && (unsigned)(Y) < (unsigned)Hh)      \
                acc += (W) * aw * (double)value[vbase + (size_t)(st + (Y) * Ww + (X)) * 64];
            CORN(x0, y0, w00) CORN(x0 + 1, y0, w10) CORN(x0, y0 + 1, w01) CORN(x0 + 1, y0 + 1, w11)
#undef CORN
        }
    }
    out[(size_t)row * 256 + h * 32 + d] = (float)acc;
}

// ------ NEW sampler: value [bslot][token][256], all 8 heads per block ---------
__global__ __launch_bounds__(256)
void deform_sample2(const float* __restrict__ value,
                    const float* __restrict__ offb, const float* __restrict__ awsm,
                    const double* __restrict__ ref, float* __restrict__ out, int row0)
{
    int row = row0 + blockIdx.x;
    int h = threadIdx.x >> 5, d = threadIdx.x & 31;
    double rx = ref[row * 4 + 0], ry = ref[row * 4 + 1];
    double rw = ref[row * 4 + 2], rh = ref[row * 4 + 3];
    const float* offr = offb + (size_t)row * 256;
    const float* awr = awsm + (size_t)row * 128 + h * 16;
    size_t vbase = (size_t)(blockIdx.x / 300) * SSP * 256 + h * 32 + d;
    const int LH[4] = {100, 50, 25, 13};
    const int LW[4] = {100, 50, 25, 13};
    const int LS[4] = {0, 10000, 12500, 13125};
    double acc = 0.;
#pragma unroll
    for (int l = 0; l < 4; l++) {
        int Hh = LH[l], Ww = LW[l], st = LS[l];
#pragma unroll
        for (int p = 0; p < 4; p++) {
            double ox = (double)offr[(h * 32) + l * 8 + p * 2 + 0];
            double oy = (double)offr[(h * 32) + l * 8 + p * 2 + 1];
            double aw = (double)awr[l * 4 + p];
            double x = (rx + ox * 0.125 * rw) * Ww - 0.5;
            double y = (ry + oy * 0.125 * rh) * Hh - 0.5;
            double xf = floor(x), yf = floor(y);
            double dx = x - xf, dy = y - yf;
            int x0 = (int)xf, y0 = (int)yf;
            double w00 = (1 - dx) * (1 - dy), w10 = dx * (1 - dy);
            double w01 = (1 - dx) * dy, w11 = dx * dy;
#define CORN(X, Y, W)                                                              \
            if ((unsigned)(X) < (unsigned)Ww && (unsigned)(Y) < (unsigned)Hh)      \
                acc += (W) * aw * (double)value[vbase + (size_t)(st + (Y) * Ww + (X)) * 256];
            CORN(x0, y0, w00) CORN(x0 + 1, y0, w10) CORN(x0, y0 + 1, w01) CORN(x0 + 1, y0 + 1, w11)
#undef CORN
        }
    }
    out[(size_t)row * 256 + h * 32 + d] = (float)acc;
}

// ---------------- ref init / update (fp64 state, fp32 refs out) ---------------
__global__ void ref_init(const float* __restrict__ lin2, const float* __restrict__ bb,
                         double* __restrict__ ref)
{
    int t = blockIdx.x * 256 + threadIdx.x;
    if (t >= NROW) return;
#pragma unroll
    for (int j = 0; j < 2; j++) {
        double r2 = sigd((double)lin2[t * 2 + j]);
        ref[t * 4 + j] = sigd((double)bb[t * 4 + j] + invsigd(r2));
    }
    ref[t * 4 + 2] = sigd((double)bb[t * 4 + 2]);
    ref[t * 4 + 3] = sigd((double)bb[t * 4 + 3]);
}
__global__ void ref_update(const float* __restrict__ bb, double* __restrict__ ref,
                           float* __restrict__ refs_out)
{
    int t = blockIdx.x * 256 + threadIdx.x;
    if (t >= NROW * 4) return;
    double nv = sigd((double)bb[t] + invsigd(ref[t]));
    ref[t] = nv;
    refs_out[t] = (float)nv;
}

// =============================== launcher =====================================
extern "C" void kernel_launch(void* const* d_in, const int* in_sizes, int n_in,
                              void* d_out, int out_size, void* d_ws, size_t ws_size,
                              hipStream_t stream)
{
    const float* src0 = (const float*)d_in[0];
    const float* src1 = (const float*)d_in[2];
    const float* src2 = (const float*)d_in[4];
    const float* src3 = (const float*)d_in[6];
    const float* qe = (const float*)d_in[8];
    const float* ref_w = (const float*)d_in[9];
    const float* ref_b = (const float*)d_in[10];
    const float* sa_in_w = (const float*)d_in[11];
    const float* sa_in_b = (const float*)d_in[12];
    const float* sa_out_w = (const float*)d_in[13];
    const float* sa_out_b = (const float*)d_in[14];
    const float* off_w = (const float*)d_in[15];
    const float* off_b = (const float*)d_in[16];
    const float* aw_w = (const float*)d_in[17];
    const float* aw_b = (const float*)d_in[18];
    const float* val_w = (const float*)d_in[19];
    const float* val_b = (const float*)d_in[20];
    const float* cao_w = (const float*)d_in[21];
    const float* cao_b = (const float*)d_in[22];
    const float* ln1_w = (const float*)d_in[23];
    const float* ln1_b = (const float*)d_in[24];
    const float* ln2_w = (const float*)d_in[25];
    const float* ln2_b = (const float*)d_in[26];
    const float* ln3_w = (const float*)d_in[27];
    const float* ln3_b = (const float*)d_in[28];
    const float* ff1_w = (const float*)d_in[29];
    const float* ff1_b = (const float*)d_in[30];
    const float* ff2_w = (const float*)d_in[31];
    const float* ff2_b = (const float*)d_in[32];
    const float* bb_w1 = (const float*)d_in[33];
    const float* bb_b1 = (const float*)d_in[34];
    const float* bb_w2 = (const float*)d_in[35];
    const float* bb_b2 = (const float*)d_in[36];
    const float* bb_w3 = (const float*)d_in[37];
    const float* bb_b3 = (const float*)d_in[38];
    const float* cls_w = (const float*)d_in[39];
    const float* cls_b = (const float*)d_in[40];

    char* wsp = (char*)d_ws;
    size_t off_ws = 0;
    auto alloc = [&](size_t bytes) -> char* {
        char* p = wsp + off_ws;
        off_ws += (bytes + 255) & ~(size_t)255;
        return p;
    };
    double* tgt  = (double*)alloc((size_t)NROWP * 256 * 8);  // 4.98 MB fp64 residual
    char* bigA = alloc((size_t)NROWP * 512 * 4);             // 4.98 union
    float* qk   = (float*)bigA;
    float* ffnh = (float*)bigA;
    float* offb = (float*)bigA;
    float* awb  = (float*)(bigA + (size_t)NROWP * 256 * 4);
    char* bufB = alloc((size_t)NROWP * 256 * 4);             // 2.49 union
    float* vbuf = (float*)bufB;
    float* samp = (float*)bufB;
    float* bh1  = (float*)bufB;
    float* bb4   = (float*)alloc((size_t)NROWP * 4 * 4);
    double* refb = (double*)alloc((size_t)NROWP * 4 * 8);
    float* rlin2 = (float*)alloc((size_t)NROWP * 2 * 4);
    size_t val_off = off_ws;
    float* proj = (float*)alloc((size_t)NROWP * 256 * 4);    // 2.49
    char* bufC  = alloc((size_t)NROWP * 256 * 4);            // 2.49 union
    float* mhab = (float*)bufC;
    float* bh2 = (float*)bufC;
    float* valueBig = proj;   // value region spans proj, bufC, and ws tail

    // path selection by available workspace beyond val_off
    size_t avail = ws_size > val_off ? ws_size - val_off : 0;
    size_t vbytes = (size_t)SSP * 256 * 4;                   // 13.6 MB per batch
    int nb = 0;
    if (avail >= 8 * vbytes + 4096) nb = 8;
    else if (avail >= 4 * vbytes + 4096) nb = 4;
    else if (avail >= 2 * vbytes + 4096) nb = 2;
    else if (avail >= 1 * vbytes + 4096) nb = 1;
    // nb==0 -> fallback 64-ch-slice path (needs 6.81 MB at val_off, proven safe)

    float* out_f = (float*)d_out;
    float* hs_out = out_f;                                   // 6 * 614400
    float* refs_out = out_f + (size_t)6 * 614400;            // 6 * 9600
    float* log_out = refs_out + (size_t)6 * 9600;            // 6 * 194400

    // ---- setup ----
    init_tgt<<<NROWP, 256, 0, stream>>>(qe, tgt);
    gemm_small_qe<<<(NROW * 2 + 255) / 256, 256, 0, stream>>>(qe, ref_w, ref_b, rlin2, 2, NROW);
    launch_m<double, true, false>(stream, tgt, 256, bb_w1, 256, bb_b1, bh1, 256, NROW, 256, 256);
    launch_m<float, true, false>(stream, bh1, 256, bb_w2, 256, bb_b2, proj, 256, NROW, 256, 256);
    gemm_smallN<<<(NROW * 4 + 255) / 256, 256, 0, stream>>>(proj, 256, bb_w3, bb_b3, bb4, 4, NROW);
    ref_init<<<(NROW + 255) / 256, 256, 0, stream>>>(rlin2, bb4, refb);

    for (int i = 0; i < 6; i++) {
        // ---- self attention (qin fused into GEMM A-read) ----
        launch_mq(stream, tgt, 256, qe, sa_in_w + (size_t)i * 196608, 256,
                  sa_in_b + i * 768, qk, 512, NROW, 512, 256);
        launch_m<double, false, false>(stream, tgt, 256, sa_in_w + (size_t)i * 196608 + 131072, 256,
                                       sa_in_b + i * 768 + 512, vbuf, 256, NROW, 256, 256);
        mha12<<<dim3(200, 8), 384, 0, stream>>>(qk, vbuf, mhab);
        launch_m<float, false, false>(stream, mhab, 256, sa_out_w + (size_t)i * 65536, 256,
                                      sa_out_b + i * 256, proj, 256, NROW, 256, 256);
        add_ln<<<NROW, 256, 0, stream>>>(tgt, proj, ln2_w + i * 256, ln2_b + i * 256, nullptr);

        // ---- deformable cross attention (qin fused into GEMM A-read) ----
        launch_mq(stream, tgt, 256, qe, off_w + (size_t)i * 65536, 256,
                  off_b + i * 256, offb, 256, NROW, 256, 256);
        launch_mq(stream, tgt, 256, qe, aw_w + (size_t)i * 32768, 256,
                  aw_b + i * 128, awb, 128, NROW, 128, 256);
        aw_softmax<<<(NROW * 8 + 255) / 256, 256, 0, stream>>>(awb);
        if (nb > 0) {
            for (int bg = 0; bg < 8 / nb; bg++) {
                value3_mgemm<<<dim3((SSP + 127) / 128, 2, nb), 256, 0, stream>>>(
                    src0, src1, src2, src3, bg * nb, val_w + (size_t)i * 65536, val_b + i * 256,
                    valueBig);
                deform_sample2<<<nb * 300, 256, 0, stream>>>(valueBig, offb, awb, refb,
                                                             samp, bg * nb * 300);
            }
        } else {
            for (int s = 0; s < 4; s++) {
                for (int bg = 0; bg < 4; bg++) {
                    value_mgemm<<<dim3((SSP + 63) / 64, 2), 256, 0, stream>>>(
                        src0, src1, src2, src3, bg * 2, val_w + (size_t)i * 65536, val_b + i * 256,
                        valueBig, s * 64);
                    deform_sample<<<600, 64, 0, stream>>>(valueBig, s * 2, offb, awb, refb,
                                                          samp, bg * 600);
                }
            }
        }
        launch_m<float, false, false>(stream, samp, 256, cao_w + (size_t)i * 65536, 256,
                                      cao_b + i * 256, proj, 256, NROW, 256, 256);
        add_ln<<<NROW, 256, 0, stream>>>(tgt, proj, ln1_w + i * 256, ln1_b + i * 256, nullptr);

        // ---- FFN, hidden split 2x512 into ffnh(bigA) ----
        launch_m<double, true, false>(stream, tgt, 256, ff1_w + (size_t)i * 262144, 256,
                                      ff1_b + i * 1024, ffnh, 512, NROW, 512, 256);
        launch_m<float, false, false>(stream, ffnh, 512, ff2_w + (size_t)i * 262144, 1024,
                                      ff2_b + i * 256, proj, 256, NROW, 256, 512);
        launch_m<double, true, false>(stream, tgt, 256, ff1_w + (size_t)i * 262144 + 512 * 256, 256,
                                      ff1_b + i * 1024 + 512, ffnh, 512, NROW, 512, 256);
        launch_m<float, false, true>(stream, ffnh, 512, ff2_w + (size_t)i * 262144 + 512, 1024,
                                     nullptr, proj, 256, NROW, 256, 512);
        add_ln<<<NROW, 256, 0, stream>>>(tgt, proj, ln3_w + i * 256, ln3_b + i * 256,
                                         hs_out + (size_t)i * 614400);

        // ---- bbox refinement: bh1(bufB), bh2(bufC) ----
        launch_m<double, true, false>(stream, tgt, 256, bb_w1 + (size_t)(i + 1) * 65536, 256,
                                      bb_b1 + (i + 1) * 256, bh1, 256, NROW, 256, 256);
        launch_m<float, true, false>(stream, bh1, 256, bb_w2 + (size_t)(i + 1) * 65536, 256,
                                     bb_b2 + (i + 1) * 256, bh2, 256, NROW, 256, 256);
        gemm_smallN<<<(NROW * 4 + 255) / 256, 256, 0, stream>>>(
            bh2, 256, bb_w3 + (size_t)(i + 1) * 1024, bb_b3 + (i + 1) * 4, bb4, 4, NROW);
        ref_update<<<(NROW * 4 + 255) / 256, 256, 0, stream>>>(bb4, refb, refs_out + (size_t)i * 9600);

        // ---- logits ----
        launch_m<double, false, false>(stream, tgt, 256, cls_w + (size_t)(i + 1) * 20736, 256,
                                       cls_b + (i + 1) * 81, log_out + (size_t)i * 194400,
                                       81, NROW, 81, 256);
    }
}